// Round 2
// baseline (224.295 us; speedup 1.0000x reference)
//
#include <hip/hip_runtime.h>
#include <cstdint>

#define TOKENS 16384
#define DMODEL 512
#define DIM    1024
#define NQ     10
#define NL     2
#define BM     128
#define BN     128
#define BK     32

typedef __bf16 bf16x8 __attribute__((ext_vector_type(8)));
typedef float  f32x4  __attribute__((ext_vector_type(4)));
typedef unsigned short u16x8 __attribute__((ext_vector_type(8)));

__device__ __forceinline__ float b2f(unsigned short h) {
    union { unsigned u; float f; } v; v.u = ((unsigned)h) << 16; return v.f;
}
__device__ __forceinline__ unsigned short f2b(float f) {
    unsigned u = __builtin_bit_cast(unsigned, f);
    return (unsigned short)((u + 0x7FFFu + ((u >> 16) & 1u)) >> 16);  // RNE
}
__device__ __forceinline__ float2 cmul(float2 a, float2 b) {
    return make_float2(a.x * b.x - a.y * b.y, a.x * b.y + a.y * b.x);
}
__device__ __forceinline__ float2 cadd(float2 a, float2 b) {
    return make_float2(a.x + b.x, a.y + b.y);
}
__device__ __forceinline__ void async_copy16(const void* g, void* l) {
    __builtin_amdgcn_global_load_lds((const __attribute__((address_space(1))) void*)g,
                                     (__attribute__((address_space(3))) void*)l, 16, 0, 0);
}

// ---------------------------------------------------------------------------
// prep_all: block-id branched fused prep.  (unchanged)
// ---------------------------------------------------------------------------
__global__ __launch_bounds__(256)
void prep_all_kernel(const float* __restrict__ x,  unsigned short* __restrict__ xb,
                     const float* __restrict__ w2, unsigned short* __restrict__ w2b,
                     const float* __restrict__ W_in, unsigned short* __restrict__ wtT,
                     const float* __restrict__ rot, const float* __restrict__ ent,
                     const float* __restrict__ bin,
                     unsigned short* __restrict__ U, float* __restrict__ b2) {
    const int bid = blockIdx.x;
    const int t = threadIdx.x;

    if (bid < 256) {
        // ---------------- buildU + b2 ----------------
        __shared__ float2 Gs[NL * NQ * 4];
        const int lane = t & 63;
        const int c = bid * 4 + (t >> 6);

        if (t < NL * NQ) {
            float tx = rot[t * 3 + 0] * 0.5f;
            float ty = rot[t * 3 + 1] * 0.5f;
            float tz = rot[t * 3 + 2] * 0.5f;
            float cx = cosf(tx), sx = sinf(tx);
            float cy = cosf(ty), sy = sinf(ty);
            float cz = cosf(tz), sz = sinf(tz);
            float2 rx00 = make_float2(cx, 0.f),  rx01 = make_float2(0.f, -sx);
            float2 rx10 = make_float2(0.f, -sx), rx11 = make_float2(cx, 0.f);
            float2 ry00 = make_float2(cy, 0.f),  ry01 = make_float2(-sy, 0.f);
            float2 ry10 = make_float2(sy, 0.f),  ry11 = make_float2(cy, 0.f);
            float2 m00 = cadd(cmul(ry00, rx00), cmul(ry01, rx10));
            float2 m01 = cadd(cmul(ry00, rx01), cmul(ry01, rx11));
            float2 m10 = cadd(cmul(ry10, rx00), cmul(ry11, rx10));
            float2 m11 = cadd(cmul(ry10, rx01), cmul(ry11, rx11));
            float2 e0 = make_float2(cz, -sz), e1 = make_float2(cz, sz);
            Gs[t * 4 + 0] = cmul(e0, m00);
            Gs[t * 4 + 1] = cmul(e0, m01);
            Gs[t * 4 + 2] = cmul(e1, m10);
            Gs[t * 4 + 3] = cmul(e1, m11);
        }
        float ef[NL * (NQ - 1)];
        #pragma unroll
        for (int i = 0; i < NL * (NQ - 1); i++) ef[i] = ent[i];
        __syncthreads();

        float2 amp[16];
        #pragma unroll
        for (int r = 0; r < 16; r++)
            amp[r] = make_float2((lane * 16 + r == c) ? 1.f : 0.f, 0.f);

        #pragma unroll 1
        for (int li = 0; li < NL; li++) {
            const int l = NL - 1 - li;
            #pragma unroll
            for (int r = 0; r < 16; r++) {
                int idx = lane * 16 + r;
                float ang = 0.f;
                #pragma unroll
                for (int q = 0; q < NQ - 1; q++) {
                    int both = ((idx >> (9 - q)) & 1) & ((idx >> (8 - q)) & 1);
                    if (both) ang += ef[l * (NQ - 1) + q];
                }
                amp[r] = cmul(amp[r], make_float2(cosf(ang), sinf(ang)));
            }
            const float2* Gl = Gs + l * NQ * 4;
            #pragma unroll
            for (int qq = 0; qq < NQ; qq++) {
                const int q = 9 - qq;
                float2 u00 = Gl[q * 4 + 0], u10 = Gl[q * 4 + 1];   // transposed:
                float2 u01 = Gl[q * 4 + 2], u11 = Gl[q * 4 + 3];   // u01<->u10
                if (q >= 6) {
                    const int S = 1 << (9 - q);
                    #pragma unroll
                    for (int r = 0; r < 16; r++) {
                        if (r & S) continue;
                        float2 a = amp[r], b = amp[r + S];
                        float2 n0, n1;
                        n0.x = u00.x * a.x - u00.y * a.y + u01.x * b.x - u01.y * b.y;
                        n0.y = u00.x * a.y + u00.y * a.x + u01.x * b.y + u01.y * b.x;
                        n1.x = u10.x * a.x - u10.y * a.y + u11.x * b.x - u11.y * b.y;
                        n1.y = u10.x * a.y + u10.y * a.x + u11.x * b.y + u11.y * b.x;
                        amp[r] = n0; amp[r + S] = n1;
                    }
                } else {
                    const int mask = 32 >> q;
                    int bit = (lane >> (5 - q)) & 1;
                    float2 ua = bit ? u11 : u00;
                    float2 ub = bit ? u10 : u01;
                    #pragma unroll
                    for (int r = 0; r < 16; r++) {
                        float px = __shfl_xor(amp[r].x, mask, 64);
                        float py = __shfl_xor(amp[r].y, mask, 64);
                        float nx = ua.x * amp[r].x - ua.y * amp[r].y + ub.x * px - ub.y * py;
                        float ny = ua.x * amp[r].y + ua.y * amp[r].x + ub.x * py + ub.y * px;
                        amp[r] = make_float2(nx, ny);
                    }
                }
            }
        }

        // b2 fold at full fp32 precision: b2[2c]=Re(U@bin), b2[2c+1]=Im
        float accRe = 0.f, accIm = 0.f;
        #pragma unroll
        for (int i = 0; i < 4; i++) {
            float4 bv = *(const float4*)&bin[lane * 16 + i * 4];
            accRe += amp[i * 4 + 0].x * bv.x + amp[i * 4 + 1].x * bv.y
                   + amp[i * 4 + 2].x * bv.z + amp[i * 4 + 3].x * bv.w;
            accIm += amp[i * 4 + 0].y * bv.x + amp[i * 4 + 1].y * bv.y
                   + amp[i * 4 + 2].y * bv.z + amp[i * 4 + 3].y * bv.w;
        }
        #pragma unroll
        for (int m = 1; m < 64; m <<= 1) {
            accRe += __shfl_xor(accRe, m, 64);
            accIm += __shfl_xor(accIm, m, 64);
        }
        if (lane == 0) { b2[2 * c] = accRe; b2[2 * c + 1] = accIm; }

        u16x8 o0, o1, p0, p1;
        #pragma unroll
        for (int r = 0; r < 8; r++) {
            o0[r] = f2b(amp[r].x);     o1[r] = f2b(amp[r + 8].x);
            p0[r] = f2b(amp[r].y);     p1[r] = f2b(amp[r + 8].y);
        }
        unsigned short* rowRe = U + (size_t)(2 * c) * DIM + lane * 16;
        unsigned short* rowIm = U + (size_t)(2 * c + 1) * DIM + lane * 16;
        *(u16x8*)rowRe = o0; *(u16x8*)(rowRe + 8) = o1;
        *(u16x8*)rowIm = p0; *(u16x8*)(rowIm + 8) = p1;
        return;
    }

    if (bid < 768) {
        // ---------------- W_in transpose -> wtT ----------------
        __shared__ float tile[32][33];
        const int b2i = bid - 256;
        const int tx = t & 31, ty = t >> 5;   // 32x8
        const int d0 = (b2i & 15) * 32, j0 = (b2i >> 4) * 32;
        #pragma unroll
        for (int i = 0; i < 32; i += 8)
            tile[ty + i][tx] = W_in[(size_t)(j0 + ty + i) * DMODEL + d0 + tx];
        __syncthreads();
        #pragma unroll
        for (int i = 0; i < 32; i += 8)
            wtT[(size_t)(d0 + ty + i) * DIM + j0 + tx] = f2b(tile[tx][ty + i]);
        return;
    }

    // ---------------- x / W_out fp32 -> bf16 ----------------
    const int NX4 = TOKENS * DMODEL / 4;
    const int NW4 = DMODEL * DIM / 4;
    const int total = NX4 + NW4;
    const int stride = 2048 * 256;
    for (int i = (bid - 768) * 256 + t; i < total; i += stride) {
        const float* s; unsigned short* d; int j;
        if (i < NX4) { s = x;  d = xb;  j = i; }
        else         { s = w2; d = w2b; j = i - NX4; }
        float4 v = *(const float4*)&s[(size_t)j * 4];
        ushort4 o;
        o.x = f2b(v.x); o.y = f2b(v.y); o.z = f2b(v.z); o.w = f2b(v.w);
        *(ushort4*)&d[(size_t)j * 4] = o;
    }
}

// ---------------------------------------------------------------------------
// fold: W1c[j,d] = sum_k Ucat[j,k] * wtT[d,k]  (unchanged)
// ---------------------------------------------------------------------------
__global__ __launch_bounds__(256)
void fold_kernel(const unsigned short* __restrict__ A, const unsigned short* __restrict__ B,
                 unsigned short* __restrict__ C) {
    __shared__ unsigned short lds_a[BM * BK];
    __shared__ unsigned short lds_b[BN * BK];
    const int t = threadIdx.x;
    const int wave = t >> 6, lane = t & 63;
    const int wm = wave >> 1, wn = wave & 1;
    const int bm0 = blockIdx.y * BM;
    const int bn0 = blockIdx.x * BN;
    const int K = DIM, N = DMODEL;

    f32x4 acc[4][4] = {};
    const int c0 = t, c1 = t + 256;
    const int r0 = c0 >> 2, g0 = (c0 & 3) ^ ((r0 >> 1) & 3);
    const int r1 = c1 >> 2, g1 = (c1 & 3) ^ ((r1 >> 1) & 3);

    for (int k0 = 0; k0 < K; k0 += BK) {
        async_copy16(A + (size_t)(bm0 + r0) * K + k0 + g0 * 8, (char*)lds_a + wave * 1024);
        async_copy16(A + (size_t)(bm0 + r1) * K + k0 + g1 * 8, (char*)lds_a + wave * 1024 + 4096);
        async_copy16(B + (size_t)(bn0 + r0) * K + k0 + g0 * 8, (char*)lds_b + wave * 1024);
        async_copy16(B + (size_t)(bn0 + r1) * K + k0 + g1 * 8, (char*)lds_b + wave * 1024 + 4096);
        __syncthreads();

        bf16x8 af[4], bfr[4];
        #pragma unroll
        for (int i = 0; i < 4; i++) {
            int row = wm * 64 + i * 16 + (lane & 15);
            int slot = (lane >> 4) ^ ((row >> 1) & 3);
            af[i] = *(const bf16x8*)&lds_a[row * BK + slot * 8];
            int nrow = wn * 64 + i * 16 + (lane & 15);
            int nslot = (lane >> 4) ^ ((nrow >> 1) & 3);
            bfr[i] = *(const bf16x8*)&lds_b[nrow * BK + nslot * 8];
        }
        #pragma unroll
        for (int i = 0; i < 4; i++)
            #pragma unroll
            for (int j = 0; j < 4; j++)
                acc[i][j] = __builtin_amdgcn_mfma_f32_16x16x32_bf16(af[i], bfr[j], acc[i][j], 0, 0, 0);
        __syncthreads();
    }

    #pragma unroll
    for (int i = 0; i < 4; i++)
        #pragma unroll
        for (int j = 0; j < 4; j++) {
            int col = bn0 + wn * 64 + j * 16 + (lane & 15);
            #pragma unroll
            for (int r = 0; r < 4; r++) {
                int row = bm0 + wm * 64 + i * 16 + (lane >> 4) * 4 + r;
                C[(size_t)row * N + col] = f2b(acc[i][j][r]);
            }
        }
}

// ---------------------------------------------------------------------------
// gemm1 v4: 256x256 tile, BK=64, 8 waves (2Mx4N), 128 KB double-buffered LDS,
// counted-vmcnt multi-phase schedule (T3+T4): each K-tile = 2 phases (kk=0/1);
// per phase: issue 4 half-tile global_load_lds -> 12 ds_read_b128 -> 32 MFMA
// (setprio-wrapped, T5) -> s_waitcnt vmcnt(4) (4 loads stay in flight ACROSS
// the raw s_barrier) -> s_barrier.  vmcnt(0) only in the tail tile.
// LDS layout per (buf,mat,kk): [256 rows][4 chunks of 16B], chunk c of row r
// stored at slot c ^ ((r>>1)&3); same involution applied to the pre-swizzled
// global source (both-sides rule) and to the ds_read side -> conflict-free.
// XCD-bijective swizzle: 8 M-tiles x all 8 N-tiles per XCD (A+B L2-resident).
// ---------------------------------------------------------------------------
__global__ __launch_bounds__(512, 2)
void gemm1_kernel(const unsigned short* __restrict__ A, const unsigned short* __restrict__ B,
                  const float* __restrict__ bias, unsigned short* __restrict__ P) {
    // elems: buf*32768 + mat*16384 + kk*8192 + row*32 + slot*8   (128 KB total)
    __shared__ unsigned short sm[2 * 32768];
    const int t = threadIdx.x;
    const int wave = t >> 6, lane = t & 63;
    const int wm = wave >> 2, wn = wave & 3;          // 2 x 4 waves
    const int laneR = lane & 15;

    const int bid = blockIdx.x;                       // 512 blocks
    const int swz = (bid & 7) * 64 + (bid >> 3);
    const int bm0 = (swz >> 3) * 256;                 // 64 M-tiles
    const int bn0 = (swz & 7) * 256;                  // 8 N-tiles

    // staging: thread t, group g in {0,1} covers chunk-id g*512+t
    //   row = g*128 + (t>>2), dest lin slot = t&3,
    //   source chunk csrc = (t&3) ^ ((row>>1)&3) = (t&3) ^ ((t>>3)&3)
    const int csrc  = (t & 3) ^ ((t >> 3) & 3);
    const int rowg  = t >> 2;
    const unsigned aOff0 = (unsigned)(bm0 + rowg) * DMODEL + csrc * 8;
    const unsigned aOff1 = (unsigned)(bm0 + 128 + rowg) * DMODEL + csrc * 8;
    const unsigned bOff0 = (unsigned)(bn0 + rowg) * DMODEL + csrc * 8;
    const unsigned bOff1 = (unsigned)(bn0 + 128 + rowg) * DMODEL + csrc * 8;

    // ds_read slot is lane-constant: slot = (lane>>4) ^ ((laneR>>1)&3)
    const int slotc = (((lane >> 4) ^ ((lane >> 1) & 3)) & 3) * 8;

    f32x4 acc[8][4] = {};

    #define G1_STAGE(nbuf, kk, kb)                                                 \
    {                                                                              \
        unsigned short* d0 = sm + (nbuf) * 32768 + (kk) * 8192 + wave * 512;       \
        async_copy16(A + aOff0 + (kb) + (kk) * 32, d0);                            \
        async_copy16(A + aOff1 + (kb) + (kk) * 32, d0 + 4096);                     \
        async_copy16(B + bOff0 + (kb) + (kk) * 32, d0 + 16384);                    \
        async_copy16(B + bOff1 + (kb) + (kk) * 32, d0 + 20480);                    \
    }

    #define G1_COMPUTE(cbuf, kk)                                                   \
    {                                                                              \
        const unsigned short* la = sm + (cbuf) * 32768 + (kk) * 8192;              \
        const unsigned short* lb = la + 16384;                                     \
        bf16x8 af[8], bfr[4];                                                      \
        _Pragma("unroll")                                                          \
        for (int i = 0; i < 8; i++)                                                \
            af[i] = *(const bf16x8*)&la[(wm * 128 + i * 16 + laneR) * 32 + slotc]; \
        _Pragma("unroll")                                                          \
        for (int j = 0; j < 4; j++)                                                \
            bfr[j] = *(const bf16x8*)&lb[(wn * 64 + j * 16 + laneR) * 32 + slotc]; \
        __builtin_amdgcn_s_setprio(1);                                             \
        _Pragma("unroll")                                                          \
        for (int i = 0; i < 8; i++)                                                \
            _Pragma("unroll")                                                      \
            for (int j = 0; j < 4; j++)                                            \
                acc[i][j] = __builtin_amdgcn_mfma_f32_16x16x32_bf16(af[i], bfr[j], acc[i][j], 0, 0, 0); \
        __builtin_amdgcn_s_setprio(0);                                             \
    }

    // prologue: stage tile 0 (both halves); wait kk0, keep kk1 in flight
    G1_STAGE(0, 0, 0);
    G1_STAGE(0, 1, 0);
    asm volatile("s_waitcnt vmcnt(4)" ::: "memory");
    asm volatile("s_barrier" ::: "memory");

    #pragma unroll
    for (int kt = 0; kt < 7; kt++) {
        const int cur = kt & 1, nxt = cur ^ 1;
        const unsigned kb = (unsigned)(kt + 1) * 64;
        // phase A (kk=0): stage kk0 of t+1; compute kk0 of t; drain kk1 of t
        G1_STAGE(nxt, 0, kb);
        G1_COMPUTE(cur, 0);
        asm volatile("s_waitcnt vmcnt(4)" ::: "memory");
        asm volatile("s_barrier" ::: "memory");
        // phase B (kk=1): stage kk1 of t+1; compute kk1 of t; drain kk0 of t+1
        G1_STAGE(nxt, 1, kb);
        G1_COMPUTE(cur, 1);
        asm volatile("s_waitcnt vmcnt(4)" ::: "memory");
        asm volatile("s_barrier" ::: "memory");
    }
    // tail tile 7 (buf 1): no staging
    G1_COMPUTE(1, 0);
    asm volatile("s_waitcnt vmcnt(0)" ::: "memory");
    asm volatile("s_barrier" ::: "memory");
    G1_COMPUTE(1, 1);

    #undef G1_STAGE
    #undef G1_COMPUTE

    // epilogue: +bias, square, pair-sum adjacent cols, write p bf16
    #pragma unroll
    for (int i = 0; i < 8; i++) {
        #pragma unroll
        for (int j = 0; j < 4; j++) {
            int col = bn0 + wn * 64 + j * 16 + laneR;
            float bv = bias[col];
            #pragma unroll
            for (int r = 0; r < 4; r++) {
                int row = bm0 + wm * 128 + i * 16 + (lane >> 4) * 4 + r;
                float val = acc[i][j][r] + bv;
                float v2 = val * val;
                float v2p = v2 + __shfl_xor(v2, 1, 64);
                if (!(lane & 1))
                    P[(size_t)row * DIM + (col >> 1)] = f2b(v2p);
            }
        }
    }
}

// ---------------------------------------------------------------------------
// gemm2_ln: out = LN( (p@W_out^T)/n2 + b_out ) * ln_w + ln_b  (unchanged)
// ---------------------------------------------------------------------------
__global__ __launch_bounds__(256)
void gemm2_ln_kernel(const unsigned short* __restrict__ A,   // p [TOKENS][DIM]
                     const unsigned short* __restrict__ B,   // w2b [DMODEL][DIM]
                     const float* __restrict__ bias,
                     const float* __restrict__ lw, const float* __restrict__ lb,
                     float* __restrict__ out) {
    __shared__ unsigned short lds_a[32 * BK];
    __shared__ unsigned short lds_b[512 * BK];
    __shared__ float redS[4][32], redQ[4][32];
    __shared__ float muS[32], rsS[32], n2s[32];
    const int t = threadIdx.x, wave = t >> 6, lane = t & 63;
    const int bm0 = blockIdx.x * 32;

    f32x4 acc[2][8] = {};
    f32x4 accN[2] = {};
    bf16x8 ones;
    #pragma unroll
    for (int r = 0; r < 8; r++) ones[r] = (__bf16)1.0f;

    const int ra = t >> 2, ga = (t & 3) ^ ((ra >> 1) & 3);

    for (int k0 = 0; k0 < DIM; k0 += BK) {
        if (wave < 2)
            async_copy16(A + (size_t)(bm0 + ra) * DIM + k0 + ga * 8,
                         (char*)lds_a + wave * 1024);
        #pragma unroll
        for (int s = 0; s < 8; s++) {
            int c = t + s * 256;
            int r = c >> 2, g = (c & 3) ^ ((r >> 1) & 3);
            async_copy16(B + (size_t)r * DIM + k0 + g * 8,
                         (char*)lds_b + s * 4096 + wave * 1024);
        }
        __syncthreads();

        bf16x8 af[2], bfr[8];
        #pragma unroll
        for (int i = 0; i < 2; i++) {
            int row = i * 16 + (lane & 15);
            int slot = (lane >> 4) ^ ((row >> 1) & 3);
            af[i] = *(const bf16x8*)&lds_a[row * BK + slot * 8];
        }
        #pragma unroll
        for (int j = 0; j < 8; j++) {
            int nrow = wave * 128 + j * 16 + (lane & 15);
            int nslot = (lane >> 4) ^ ((nrow >> 1) & 3);
            bfr[j] = *(const bf16x8*)&lds_b[nrow * BK + nslot * 8];
        }
        #pragma unroll
        for (int i = 0; i < 2; i++)
            #pragma unroll
            for (int j = 0; j < 8; j++)
                acc[i][j] = __builtin_amdgcn_mfma_f32_16x16x32_bf16(af[i], bfr[j], acc[i][j], 0, 0, 0);
        if (wave == 0) {
            #pragma unroll
            for (int i = 0; i < 2; i++)
                accN[i] = __builtin_amdgcn_mfma_f32_16x16x32_bf16(af[i], ones, accN[i], 0, 0, 0);
        }
        __syncthreads();
    }

    if (wave == 0 && (lane & 15) == 0) {
        #pragma unroll
        for (int i = 0; i < 2; i++)
            #pragma unroll
            for (int r = 0; r < 4; r++)
                n2s[i * 16 + (lane >> 4) * 4 + r] = accN[i][r];
    }
    __syncthreads();

    const int colb = wave * 128;
    float nn[8];
    #pragma unroll
    for (int i = 0; i < 2; i++)
        #pragma unroll
        for (int r = 0; r < 4; r++) {
            int rl = i * 16 + (lane >> 4) * 4 + r;
            nn[i * 4 + r] = 1.0f / fmaxf(n2s[rl], 1e-24f);
        }
    float pS[8], pQ[8];
    #pragma unroll
    for (int i = 0; i < 2; i++)
        #pragma unroll
        for (int r = 0; r < 4; r++) {
            float s = 0.f, q = 0.f;
            #pragma unroll
            for (int j = 0; j < 8; j++) {
                int col = colb + j * 16 + (lane & 15);
                float val = acc[i][j][r] * nn[i * 4 + r] + bias[col];
                acc[i][j][r] = val;
                s += val; q += val * val;
            }
            s += __shfl_xor(s, 1, 64); q += __shfl_xor(q, 1, 64);
            s += __shfl_xor(s, 2, 64); q += __shfl_xor(q, 2, 64);
            s += __shfl_xor(s, 4, 64); q += __shfl_xor(q, 4, 64);
            s += __shfl_xor(s, 8, 64); q += __shfl_xor(q, 8, 64);
            pS[i * 4 + r] = s; pQ[i * 4 + r] = q;
        }
    if ((lane & 15) == 0) {
        #pragma unroll
        for (int i = 0; i < 2; i++)
            #pragma unroll
            for (int r = 0; r < 4; r++) {
                int rl = i * 16 + (lane >> 4) * 4 + r;
                redS[wave][rl] = pS[i * 4 + r];
                redQ[wave][rl] = pQ[i * 4 + r];
            }
    }
    __syncthreads();
    if (t < 32) {
        float s = redS[0][t] + redS[1][t] + redS[2][t] + redS[3][t];
        float q = redQ[0][t] + redQ[1][t] + redQ[2][t] + redQ[3][t];
        float mu = s * (1.0f / DMODEL);
        float var = q * (1.0f / DMODEL) - mu * mu;
        muS[t] = mu;
        rsS[t] = rsqrtf(var + 1e-5f);
    }
    __syncthreads();
    #pragma unroll
    for (int i = 0; i < 2; i++)
        #pragma unroll
        for (int j = 0; j < 8; j++) {
            int col = colb + j * 16 + (lane & 15);
            float w = lw[col], bb = lb[col];
            #pragma unroll
            for (int r = 0; r < 4; r++) {
                int rl = i * 16 + (lane >> 4) * 4 + r;
                out[(size_t)(bm0 + rl) * DMODEL + col] =
                    (acc[i][j][r] - muS[rl]) * rsS[rl] * w + bb;
            }
        }
}

extern "C" void kernel_launch(void* const* d_in, const int* in_sizes, int n_in,
                              void* d_out, int out_size, void* d_ws, size_t ws_size,
                              hipStream_t stream) {
    (void)in_sizes; (void)n_in; (void)out_size; (void)ws_size;
    const float* x     = (const float*)d_in[0];
    const float* W_in  = (const float*)d_in[1];
    const float* b_in  = (const float*)d_in[2];
    const float* W_out = (const float*)d_in[3];
    const float* b_out = (const float*)d_in[4];
    const float* rot   = (const float*)d_in[5];
    const float* ent   = (const float*)d_in[6];
    const float* ln_w  = (const float*)d_in[7];
    const float* ln_b  = (const float*)d_in[8];
    float* out = (float*)d_out;

    char* ws = (char*)d_ws;
    unsigned short* p    = (unsigned short*)ws;                     // [16384][1024] 32 MB
    unsigned short* x_bf = (unsigned short*)(ws + 33554432ull);     // 16 MB
    unsigned short* wtT  = (unsigned short*)(ws + 50331648ull);     // [512][1024] 1 MB
    unsigned short* w2b  = (unsigned short*)(ws + 51380224ull);     // [512][1024] 1 MB
    unsigned short* Ucat = (unsigned short*)(ws + 52428800ull);     // [2048][1024] 4 MB
    unsigned short* W1c  = (unsigned short*)(ws + 56623104ull);     // [2048][512] 2 MB
    float*          b2   = (float*)(ws + 58720256ull);              // [2048] 8 KB
    // high-water ~56 MB

    prep_all_kernel<<<2816, 256, 0, stream>>>(x, x_bf, W_out, w2b, W_in, wtT,
                                              rot, ent, b_in, Ucat, b2);
    fold_kernel<<<dim3(DMODEL / BN, 2 * DIM / BM), 256, 0, stream>>>(Ucat, wtT, W1c);
    gemm1_kernel<<<512, 512, 0, stream>>>(x_bf, W1c, b2, p);
    gemm2_ln_kernel<<<TOKENS / 32, 256, 0, stream>>>(
        p, w2b, b_out, ln_w, ln_b, out);
}

// Round 3
// 219.230 us; speedup vs baseline: 1.0231x; 1.0231x over previous
//
#include <hip/hip_runtime.h>
#include <cstdint>

#define TOKENS 16384
#define DMODEL 512
#define DIM    1024
#define NQ     10
#define NL     2
#define BM     128
#define BN     128
#define BK     32

typedef __bf16 bf16x8 __attribute__((ext_vector_type(8)));
typedef float  f32x4  __attribute__((ext_vector_type(4)));
typedef unsigned short u16x8 __attribute__((ext_vector_type(8)));

__device__ __forceinline__ float b2f(unsigned short h) {
    union { unsigned u; float f; } v; v.u = ((unsigned)h) << 16; return v.f;
}
__device__ __forceinline__ unsigned short f2b(float f) {
    unsigned u = __builtin_bit_cast(unsigned, f);
    return (unsigned short)((u + 0x7FFFu + ((u >> 16) & 1u)) >> 16);  // RNE
}
__device__ __forceinline__ float2 cmul(float2 a, float2 b) {
    return make_float2(a.x * b.x - a.y * b.y, a.x * b.y + a.y * b.x);
}
__device__ __forceinline__ float2 cadd(float2 a, float2 b) {
    return make_float2(a.x + b.x, a.y + b.y);
}
__device__ __forceinline__ void async_copy16(const void* g, void* l) {
    __builtin_amdgcn_global_load_lds((const __attribute__((address_space(1))) void*)g,
                                     (__attribute__((address_space(3))) void*)l, 16, 0, 0);
}

// ---------------------------------------------------------------------------
// prep_all: block-id branched fused prep.  (unchanged)
// ---------------------------------------------------------------------------
__global__ __launch_bounds__(256)
void prep_all_kernel(const float* __restrict__ x,  unsigned short* __restrict__ xb,
                     const float* __restrict__ w2, unsigned short* __restrict__ w2b,
                     const float* __restrict__ W_in, unsigned short* __restrict__ wtT,
                     const float* __restrict__ rot, const float* __restrict__ ent,
                     const float* __restrict__ bin,
                     unsigned short* __restrict__ U, float* __restrict__ b2) {
    const int bid = blockIdx.x;
    const int t = threadIdx.x;

    if (bid < 256) {
        // ---------------- buildU + b2 ----------------
        __shared__ float2 Gs[NL * NQ * 4];
        const int lane = t & 63;
        const int c = bid * 4 + (t >> 6);

        if (t < NL * NQ) {
            float tx = rot[t * 3 + 0] * 0.5f;
            float ty = rot[t * 3 + 1] * 0.5f;
            float tz = rot[t * 3 + 2] * 0.5f;
            float cx = cosf(tx), sx = sinf(tx);
            float cy = cosf(ty), sy = sinf(ty);
            float cz = cosf(tz), sz = sinf(tz);
            float2 rx00 = make_float2(cx, 0.f),  rx01 = make_float2(0.f, -sx);
            float2 rx10 = make_float2(0.f, -sx), rx11 = make_float2(cx, 0.f);
            float2 ry00 = make_float2(cy, 0.f),  ry01 = make_float2(-sy, 0.f);
            float2 ry10 = make_float2(sy, 0.f),  ry11 = make_float2(cy, 0.f);
            float2 m00 = cadd(cmul(ry00, rx00), cmul(ry01, rx10));
            float2 m01 = cadd(cmul(ry00, rx01), cmul(ry01, rx11));
            float2 m10 = cadd(cmul(ry10, rx00), cmul(ry11, rx10));
            float2 m11 = cadd(cmul(ry10, rx01), cmul(ry11, rx11));
            float2 e0 = make_float2(cz, -sz), e1 = make_float2(cz, sz);
            Gs[t * 4 + 0] = cmul(e0, m00);
            Gs[t * 4 + 1] = cmul(e0, m01);
            Gs[t * 4 + 2] = cmul(e1, m10);
            Gs[t * 4 + 3] = cmul(e1, m11);
        }
        float ef[NL * (NQ - 1)];
        #pragma unroll
        for (int i = 0; i < NL * (NQ - 1); i++) ef[i] = ent[i];
        __syncthreads();

        float2 amp[16];
        #pragma unroll
        for (int r = 0; r < 16; r++)
            amp[r] = make_float2((lane * 16 + r == c) ? 1.f : 0.f, 0.f);

        #pragma unroll 1
        for (int li = 0; li < NL; li++) {
            const int l = NL - 1 - li;
            #pragma unroll
            for (int r = 0; r < 16; r++) {
                int idx = lane * 16 + r;
                float ang = 0.f;
                #pragma unroll
                for (int q = 0; q < NQ - 1; q++) {
                    int both = ((idx >> (9 - q)) & 1) & ((idx >> (8 - q)) & 1);
                    if (both) ang += ef[l * (NQ - 1) + q];
                }
                amp[r] = cmul(amp[r], make_float2(cosf(ang), sinf(ang)));
            }
            const float2* Gl = Gs + l * NQ * 4;
            #pragma unroll
            for (int qq = 0; qq < NQ; qq++) {
                const int q = 9 - qq;
                float2 u00 = Gl[q * 4 + 0], u10 = Gl[q * 4 + 1];   // transposed:
                float2 u01 = Gl[q * 4 + 2], u11 = Gl[q * 4 + 3];   // u01<->u10
                if (q >= 6) {
                    const int S = 1 << (9 - q);
                    #pragma unroll
                    for (int r = 0; r < 16; r++) {
                        if (r & S) continue;
                        float2 a = amp[r], b = amp[r + S];
                        float2 n0, n1;
                        n0.x = u00.x * a.x - u00.y * a.y + u01.x * b.x - u01.y * b.y;
                        n0.y = u00.x * a.y + u00.y * a.x + u01.x * b.y + u01.y * b.x;
                        n1.x = u10.x * a.x - u10.y * a.y + u11.x * b.x - u11.y * b.y;
                        n1.y = u10.x * a.y + u10.y * a.x + u11.x * b.y + u11.y * b.x;
                        amp[r] = n0; amp[r + S] = n1;
                    }
                } else {
                    const int mask = 32 >> q;
                    int bit = (lane >> (5 - q)) & 1;
                    float2 ua = bit ? u11 : u00;
                    float2 ub = bit ? u10 : u01;
                    #pragma unroll
                    for (int r = 0; r < 16; r++) {
                        float px = __shfl_xor(amp[r].x, mask, 64);
                        float py = __shfl_xor(amp[r].y, mask, 64);
                        float nx = ua.x * amp[r].x - ua.y * amp[r].y + ub.x * px - ub.y * py;
                        float ny = ua.x * amp[r].y + ua.y * amp[r].x + ub.x * py + ub.y * px;
                        amp[r] = make_float2(nx, ny);
                    }
                }
            }
        }

        // b2 fold at full fp32 precision: b2[2c]=Re(U@bin), b2[2c+1]=Im
        float accRe = 0.f, accIm = 0.f;
        #pragma unroll
        for (int i = 0; i < 4; i++) {
            float4 bv = *(const float4*)&bin[lane * 16 + i * 4];
            accRe += amp[i * 4 + 0].x * bv.x + amp[i * 4 + 1].x * bv.y
                   + amp[i * 4 + 2].x * bv.z + amp[i * 4 + 3].x * bv.w;
            accIm += amp[i * 4 + 0].y * bv.x + amp[i * 4 + 1].y * bv.y
                   + amp[i * 4 + 2].y * bv.z + amp[i * 4 + 3].y * bv.w;
        }
        #pragma unroll
        for (int m = 1; m < 64; m <<= 1) {
            accRe += __shfl_xor(accRe, m, 64);
            accIm += __shfl_xor(accIm, m, 64);
        }
        if (lane == 0) { b2[2 * c] = accRe; b2[2 * c + 1] = accIm; }

        u16x8 o0, o1, p0, p1;
        #pragma unroll
        for (int r = 0; r < 8; r++) {
            o0[r] = f2b(amp[r].x);     o1[r] = f2b(amp[r + 8].x);
            p0[r] = f2b(amp[r].y);     p1[r] = f2b(amp[r + 8].y);
        }
        unsigned short* rowRe = U + (size_t)(2 * c) * DIM + lane * 16;
        unsigned short* rowIm = U + (size_t)(2 * c + 1) * DIM + lane * 16;
        *(u16x8*)rowRe = o0; *(u16x8*)(rowRe + 8) = o1;
        *(u16x8*)rowIm = p0; *(u16x8*)(rowIm + 8) = p1;
        return;
    }

    if (bid < 768) {
        // ---------------- W_in transpose -> wtT ----------------
        __shared__ float tile[32][33];
        const int b2i = bid - 256;
        const int tx = t & 31, ty = t >> 5;   // 32x8
        const int d0 = (b2i & 15) * 32, j0 = (b2i >> 4) * 32;
        #pragma unroll
        for (int i = 0; i < 32; i += 8)
            tile[ty + i][tx] = W_in[(size_t)(j0 + ty + i) * DMODEL + d0 + tx];
        __syncthreads();
        #pragma unroll
        for (int i = 0; i < 32; i += 8)
            wtT[(size_t)(d0 + ty + i) * DIM + j0 + tx] = f2b(tile[tx][ty + i]);
        return;
    }

    // ---------------- x / W_out fp32 -> bf16 ----------------
    const int NX4 = TOKENS * DMODEL / 4;
    const int NW4 = DMODEL * DIM / 4;
    const int total = NX4 + NW4;
    const int stride = 2048 * 256;
    for (int i = (bid - 768) * 256 + t; i < total; i += stride) {
        const float* s; unsigned short* d; int j;
        if (i < NX4) { s = x;  d = xb;  j = i; }
        else         { s = w2; d = w2b; j = i - NX4; }
        float4 v = *(const float4*)&s[(size_t)j * 4];
        ushort4 o;
        o.x = f2b(v.x); o.y = f2b(v.y); o.z = f2b(v.z); o.w = f2b(v.w);
        *(ushort4*)&d[(size_t)j * 4] = o;
    }
}

// ---------------------------------------------------------------------------
// fold: W1c[j,d] = sum_k Ucat[j,k] * wtT[d,k]  (unchanged)
// ---------------------------------------------------------------------------
__global__ __launch_bounds__(256)
void fold_kernel(const unsigned short* __restrict__ A, const unsigned short* __restrict__ B,
                 unsigned short* __restrict__ C) {
    __shared__ unsigned short lds_a[BM * BK];
    __shared__ unsigned short lds_b[BN * BK];
    const int t = threadIdx.x;
    const int wave = t >> 6, lane = t & 63;
    const int wm = wave >> 1, wn = wave & 1;
    const int bm0 = blockIdx.y * BM;
    const int bn0 = blockIdx.x * BN;
    const int K = DIM, N = DMODEL;

    f32x4 acc[4][4] = {};
    const int c0 = t, c1 = t + 256;
    const int r0 = c0 >> 2, g0 = (c0 & 3) ^ ((r0 >> 1) & 3);
    const int r1 = c1 >> 2, g1 = (c1 & 3) ^ ((r1 >> 1) & 3);

    for (int k0 = 0; k0 < K; k0 += BK) {
        async_copy16(A + (size_t)(bm0 + r0) * K + k0 + g0 * 8, (char*)lds_a + wave * 1024);
        async_copy16(A + (size_t)(bm0 + r1) * K + k0 + g1 * 8, (char*)lds_a + wave * 1024 + 4096);
        async_copy16(B + (size_t)(bn0 + r0) * K + k0 + g0 * 8, (char*)lds_b + wave * 1024);
        async_copy16(B + (size_t)(bn0 + r1) * K + k0 + g1 * 8, (char*)lds_b + wave * 1024 + 4096);
        __syncthreads();

        bf16x8 af[4], bfr[4];
        #pragma unroll
        for (int i = 0; i < 4; i++) {
            int row = wm * 64 + i * 16 + (lane & 15);
            int slot = (lane >> 4) ^ ((row >> 1) & 3);
            af[i] = *(const bf16x8*)&lds_a[row * BK + slot * 8];
            int nrow = wn * 64 + i * 16 + (lane & 15);
            int nslot = (lane >> 4) ^ ((nrow >> 1) & 3);
            bfr[i] = *(const bf16x8*)&lds_b[nrow * BK + nslot * 8];
        }
        #pragma unroll
        for (int i = 0; i < 4; i++)
            #pragma unroll
            for (int j = 0; j < 4; j++)
                acc[i][j] = __builtin_amdgcn_mfma_f32_16x16x32_bf16(af[i], bfr[j], acc[i][j], 0, 0, 0);
        __syncthreads();
    }

    #pragma unroll
    for (int i = 0; i < 4; i++)
        #pragma unroll
        for (int j = 0; j < 4; j++) {
            int col = bn0 + wn * 64 + j * 16 + (lane & 15);
            #pragma unroll
            for (int r = 0; r < 4; r++) {
                int row = bm0 + wm * 64 + i * 16 + (lane >> 4) * 4 + r;
                C[(size_t)row * N + col] = f2b(acc[i][j][r]);
            }
        }
}

// ---------------------------------------------------------------------------
// gemm1 v5: 256x256, BK=64, 8 waves (2Mx4N), 128 KB dbuf — 8-phase template
// (4 phases per K-tile, 2 K-tiles per LDS generation):
//   phase = { ds_read fragment-subset ; stage ; s_barrier ; setprio(1) ;
//             16 MFMA (one C-quadrant) ; setprio(0) ; s_barrier }
// Quadrant order (gray): (0,0)->(0,1)->(1,1)->(1,0); fragments read
// non-redundantly (24 ds_read_b128 / K-tile) and held in registers.
// Staging: B(n+2) at p2 (B-frag reads done at p1), A(n+2) at p3 (A-frag
// reads done at p2) -> every region staged >=1 barrier after last read.
// vmcnt(8) once per K-tile at p3 end (retires tile n+1; tile n+2's 8 loads
// stay in flight across the barrier). Tail: vmcnt(0) at n==6.
// ---------------------------------------------------------------------------
__global__ __launch_bounds__(512, 2)
void gemm1_kernel(const unsigned short* __restrict__ A, const unsigned short* __restrict__ B,
                  const float* __restrict__ bias, unsigned short* __restrict__ P) {
    // elems: buf*32768 + mat*16384 + kk*8192 + row*32 + slot*8   (128 KB)
    __shared__ unsigned short sm[2 * 32768];
    const int t = threadIdx.x;
    const int wave = t >> 6, lane = t & 63;
    const int wm = wave >> 2, wn = wave & 3;          // 2 x 4 waves
    const int laneR = lane & 15;

    const int bid = blockIdx.x;                       // 512 blocks
    const int swz = (bid & 7) * 64 + (bid >> 3);
    const int bm0 = (swz >> 3) * 256;                 // 64 M-tiles
    const int bn0 = (swz & 7) * 256;                  // 8 N-tiles

    // staging: thread t covers chunks t (g0: rows 0-127) and 512+t (g1)
    //   row = g*128 + (t>>2), dest lin slot = t&3, src slot = (t&3)^((row>>1)&3)
    const int csrc = (t & 3) ^ ((t >> 3) & 3);
    const int rowg = t >> 2;
    const unsigned aOff0 = (unsigned)(bm0 + rowg) * DMODEL + csrc * 8;
    const unsigned aOff1 = (unsigned)(bm0 + 128 + rowg) * DMODEL + csrc * 8;
    const unsigned bOff0 = (unsigned)(bn0 + rowg) * DMODEL + csrc * 8;
    const unsigned bOff1 = (unsigned)(bn0 + 128 + rowg) * DMODEL + csrc * 8;

    // ds_read slot (lane-constant): (lane>>4) ^ ((row>>1)&3), row = 16m + laneR
    const int slotc = (((lane >> 4) ^ ((lane >> 1) & 3)) & 3) * 8;

    f32x4 acc[8][4] = {};

    // stage all of B (4 half-tiles' worth = 4 loads/thread) of `tile` into buf
    #define STAGE_B4(nbuf, tile) {                                        \
        unsigned short* d = sm + (nbuf) * 32768 + 16384 + wave * 512;     \
        async_copy16(B + bOff0 + (tile) * 64,      d);                    \
        async_copy16(B + bOff1 + (tile) * 64,      d + 4096);             \
        async_copy16(B + bOff0 + (tile) * 64 + 32, d + 8192);             \
        async_copy16(B + bOff1 + (tile) * 64 + 32, d + 12288);            \
    }
    #define STAGE_A4(nbuf, tile) {                                        \
        unsigned short* d = sm + (nbuf) * 32768 + wave * 512;             \
        async_copy16(A + aOff0 + (tile) * 64,      d);                    \
        async_copy16(A + aOff1 + (tile) * 64,      d + 4096);             \
        async_copy16(A + aOff0 + (tile) * 64 + 32, d + 8192);             \
        async_copy16(A + aOff1 + (tile) * 64 + 32, d + 12288);            \
    }
    #define BARRIER()  asm volatile("s_barrier" ::: "memory")

    // prologue: fully stage tiles 0 and 1 (16 loads); retire tile 0 (vmcnt(8))
    STAGE_B4(0, 0); STAGE_A4(0, 0);
    STAGE_B4(1, 1); STAGE_A4(1, 1);
    asm volatile("s_waitcnt vmcnt(8)" ::: "memory");
    BARRIER();

    #pragma unroll
    for (int n = 0; n < 8; n++) {
        const int cb = n & 1;
        const unsigned short* la = sm + cb * 32768;
        const unsigned short* lb = la + 16384;
        bf16x8 afv[4][2], bfv[4][2];

        // ---- phase 0: read af[0..3]x2 + bfr[0..1]x2 (12); MFMA q(0,0)
        #pragma unroll
        for (int kk = 0; kk < 2; kk++) {
            #pragma unroll
            for (int i = 0; i < 4; i++)
                afv[i][kk] = *(const bf16x8*)&la[kk * 8192 + (wm * 128 + i * 16 + laneR) * 32 + slotc];
            #pragma unroll
            for (int j = 0; j < 2; j++)
                bfv[j][kk] = *(const bf16x8*)&lb[kk * 8192 + (wn * 64 + j * 16 + laneR) * 32 + slotc];
        }
        BARRIER();
        __builtin_amdgcn_sched_barrier(0);
        __builtin_amdgcn_s_setprio(1);
        #pragma unroll
        for (int i = 0; i < 4; i++)
            #pragma unroll
            for (int j = 0; j < 2; j++)
                #pragma unroll
                for (int kk = 0; kk < 2; kk++)
                    acc[i][j] = __builtin_amdgcn_mfma_f32_16x16x32_bf16(afv[i][kk], bfv[j][kk], acc[i][j], 0, 0, 0);
        __builtin_amdgcn_s_setprio(0);
        __builtin_amdgcn_sched_barrier(0);
        BARRIER();

        // ---- phase 1: read bfr[2..3]x2 (4); MFMA q(0,1)
        #pragma unroll
        for (int kk = 0; kk < 2; kk++)
            #pragma unroll
            for (int j = 2; j < 4; j++)
                bfv[j][kk] = *(const bf16x8*)&lb[kk * 8192 + (wn * 64 + j * 16 + laneR) * 32 + slotc];
        BARRIER();
        __builtin_amdgcn_sched_barrier(0);
        __builtin_amdgcn_s_setprio(1);
        #pragma unroll
        for (int i = 0; i < 4; i++)
            #pragma unroll
            for (int j = 2; j < 4; j++)
                #pragma unroll
                for (int kk = 0; kk < 2; kk++)
                    acc[i][j] = __builtin_amdgcn_mfma_f32_16x16x32_bf16(afv[i][kk], bfv[j][kk], acc[i][j], 0, 0, 0);
        __builtin_amdgcn_s_setprio(0);
        __builtin_amdgcn_sched_barrier(0);
        BARRIER();

        // ---- phase 2: read af[4..7]x2 (8, reuse afv); stage B(n+2); MFMA q(1,1)
        #pragma unroll
        for (int kk = 0; kk < 2; kk++)
            #pragma unroll
            for (int i = 0; i < 4; i++)
                afv[i][kk] = *(const bf16x8*)&la[kk * 8192 + (wm * 128 + 64 + i * 16 + laneR) * 32 + slotc];
        if (n < 6) STAGE_B4(cb, n + 2);
        BARRIER();
        __builtin_amdgcn_sched_barrier(0);
        __builtin_amdgcn_s_setprio(1);
        #pragma unroll
        for (int i = 0; i < 4; i++)
            #pragma unroll
            for (int j = 2; j < 4; j++)
                #pragma unroll
                for (int kk = 0; kk < 2; kk++)
                    acc[4 + i][j] = __builtin_amdgcn_mfma_f32_16x16x32_bf16(afv[i][kk], bfv[j][kk], acc[4 + i][j], 0, 0, 0);
        __builtin_amdgcn_s_setprio(0);
        __builtin_amdgcn_sched_barrier(0);
        BARRIER();

        // ---- phase 3: stage A(n+2); MFMA q(1,0); vmcnt once per K-tile
        if (n < 6) STAGE_A4(cb, n + 2);
        BARRIER();
        __builtin_amdgcn_sched_barrier(0);
        __builtin_amdgcn_s_setprio(1);
        #pragma unroll
        for (int i = 0; i < 4; i++)
            #pragma unroll
            for (int j = 0; j < 2; j++)
                #pragma unroll
                for (int kk = 0; kk < 2; kk++)
                    acc[4 + i][j] = __builtin_amdgcn_mfma_f32_16x16x32_bf16(afv[i][kk], bfv[j][kk], acc[4 + i][j], 0, 0, 0);
        __builtin_amdgcn_s_setprio(0);
        __builtin_amdgcn_sched_barrier(0);
        if (n < 6)      { asm volatile("s_waitcnt vmcnt(8)" ::: "memory"); }
        else if (n == 6){ asm volatile("s_waitcnt vmcnt(0)" ::: "memory"); }
        BARRIER();
    }
    #undef STAGE_A4
    #undef STAGE_B4
    #undef BARRIER

    // epilogue: +bias, square, pair-sum adjacent cols, write p bf16
    #pragma unroll
    for (int i = 0; i < 8; i++) {
        #pragma unroll
        for (int j = 0; j < 4; j++) {
            int col = bn0 + wn * 64 + j * 16 + laneR;
            float bv = bias[col];
            #pragma unroll
            for (int r = 0; r < 4; r++) {
                int row = bm0 + wm * 128 + i * 16 + (lane >> 4) * 4 + r;
                float val = acc[i][j][r] + bv;
                float v2 = val * val;
                float v2p = v2 + __shfl_xor(v2, 1, 64);
                if (!(lane & 1))
                    P[(size_t)row * DIM + (col >> 1)] = f2b(v2p);
            }
        }
    }
}

// ---------------------------------------------------------------------------
// gemm2_ln: out = LN( (p@W_out^T)/n2 + b_out ) * ln_w + ln_b  (unchanged)
// ---------------------------------------------------------------------------
__global__ __launch_bounds__(256)
void gemm2_ln_kernel(const unsigned short* __restrict__ A,   // p [TOKENS][DIM]
                     const unsigned short* __restrict__ B,   // w2b [DMODEL][DIM]
                     const float* __restrict__ bias,
                     const float* __restrict__ lw, const float* __restrict__ lb,
                     float* __restrict__ out) {
    __shared__ unsigned short lds_a[32 * BK];
    __shared__ unsigned short lds_b[512 * BK];
    __shared__ float redS[4][32], redQ[4][32];
    __shared__ float muS[32], rsS[32], n2s[32];
    const int t = threadIdx.x, wave = t >> 6, lane = t & 63;
    const int bm0 = blockIdx.x * 32;

    f32x4 acc[2][8] = {};
    f32x4 accN[2] = {};
    bf16x8 ones;
    #pragma unroll
    for (int r = 0; r < 8; r++) ones[r] = (__bf16)1.0f;

    const int ra = t >> 2, ga = (t & 3) ^ ((ra >> 1) & 3);

    for (int k0 = 0; k0 < DIM; k0 += BK) {
        if (wave < 2)
            async_copy16(A + (size_t)(bm0 + ra) * DIM + k0 + ga * 8,
                         (char*)lds_a + wave * 1024);
        #pragma unroll
        for (int s = 0; s < 8; s++) {
            int c = t + s * 256;
            int r = c >> 2, g = (c & 3) ^ ((r >> 1) & 3);
            async_copy16(B + (size_t)r * DIM + k0 + g * 8,
                         (char*)lds_b + s * 4096 + wave * 1024);
        }
        __syncthreads();

        bf16x8 af[2], bfr[8];
        #pragma unroll
        for (int i = 0; i < 2; i++) {
            int row = i * 16 + (lane & 15);
            int slot = (lane >> 4) ^ ((row >> 1) & 3);
            af[i] = *(const bf16x8*)&lds_a[row * BK + slot * 8];
        }
        #pragma unroll
        for (int j = 0; j < 8; j++) {
            int nrow = wave * 128 + j * 16 + (lane & 15);
            int nslot = (lane >> 4) ^ ((nrow >> 1) & 3);
            bfr[j] = *(const bf16x8*)&lds_b[nrow * BK + nslot * 8];
        }
        #pragma unroll
        for (int i = 0; i < 2; i++)
            #pragma unroll
            for (int j = 0; j < 8; j++)
                acc[i][j] = __builtin_amdgcn_mfma_f32_16x16x32_bf16(af[i], bfr[j], acc[i][j], 0, 0, 0);
        if (wave == 0) {
            #pragma unroll
            for (int i = 0; i < 2; i++)
                accN[i] = __builtin_amdgcn_mfma_f32_16x16x32_bf16(af[i], ones, accN[i], 0, 0, 0);
        }
        __syncthreads();
    }

    if (wave == 0 && (lane & 15) == 0) {
        #pragma unroll
        for (int i = 0; i < 2; i++)
            #pragma unroll
            for (int r = 0; r < 4; r++)
                n2s[i * 16 + (lane >> 4) * 4 + r] = accN[i][r];
    }
    __syncthreads();

    const int colb = wave * 128;
    float nn[8];
    #pragma unroll
    for (int i = 0; i < 2; i++)
        #pragma unroll
        for (int r = 0; r < 4; r++) {
            int rl = i * 16 + (lane >> 4) * 4 + r;
            nn[i * 4 + r] = 1.0f / fmaxf(n2s[rl], 1e-24f);
        }
    float pS[8], pQ[8];
    #pragma unroll
    for (int i = 0; i < 2; i++)
        #pragma unroll
        for (int r = 0; r < 4; r++) {
            float s = 0.f, q = 0.f;
            #pragma unroll
            for (int j = 0; j < 8; j++) {
                int col = colb + j * 16 + (lane & 15);
                float val = acc[i][j][r] * nn[i * 4 + r] + bias[col];
                acc[i][j][r] = val;
                s += val; q += val * val;
            }
            s += __shfl_xor(s, 1, 64); q += __shfl_xor(q, 1, 64);
            s += __shfl_xor(s, 2, 64); q += __shfl_xor(q, 2, 64);
            s += __shfl_xor(s, 4, 64); q += __shfl_xor(q, 4, 64);
            s += __shfl_xor(s, 8, 64); q += __shfl_xor(q, 8, 64);
            pS[i * 4 + r] = s; pQ[i * 4 + r] = q;
        }
    if ((lane & 15) == 0) {
        #pragma unroll
        for (int i = 0; i < 2; i++)
            #pragma unroll
            for (int r = 0; r < 4; r++) {
                int rl = i * 16 + (lane >> 4) * 4 + r;
                redS[wave][rl] = pS[i * 4 + r];
                redQ[wave][rl] = pQ[i * 4 + r];
            }
    }
    __syncthreads();
    if (t < 32) {
        float s = redS[0][t] + redS[1][t] + redS[2][t] + redS[3][t];
        float q = redQ[0][t] + redQ[1][t] + redQ[2][t] + redQ[3][t];
        float mu = s * (1.0f / DMODEL);
        float var = q * (1.0f / DMODEL) - mu * mu;
        muS[t] = mu;
        rsS[t] = rsqrtf(var + 1e-5f);
    }
    __syncthreads();
    #pragma unroll
    for (int i = 0; i < 2; i++)
        #pragma unroll
        for (int j = 0; j < 8; j++) {
            int col = colb + j * 16 + (lane & 15);
            float w = lw[col], bb = lb[col];
            #pragma unroll
            for (int r = 0; r < 4; r++) {
                int rl = i * 16 + (lane >> 4) * 4 + r;
                out[(size_t)(bm0 + rl) * DMODEL + col] =
                    (acc[i][j][r] - muS[rl]) * rsS[rl] * w + bb;
            }
        }
}

extern "C" void kernel_launch(void* const* d_in, const int* in_sizes, int n_in,
                              void* d_out, int out_size, void* d_ws, size_t ws_size,
                              hipStream_t stream) {
    (void)in_sizes; (void)n_in; (void)out_size; (void)ws_size;
    const float* x     = (const float*)d_in[0];
    const float* W_in  = (const float*)d_in[1];
    const float* b_in  = (const float*)d_in[2];
    const float* W_out = (const float*)d_in[3];
    const float* b_out = (const float*)d_in[4];
    const float* rot   = (const float*)d_in[5];
    const float* ent   = (const float*)d_in[6];
    const float* ln_w  = (const float*)d_in[7];
    const float* ln_b  = (const float*)d_in[8];
    float* out = (float*)d_out;

    char* ws = (char*)d_ws;
    unsigned short* p    = (unsigned short*)ws;                     // [16384][1024] 32 MB
    unsigned short* x_bf = (unsigned short*)(ws + 33554432ull);     // 16 MB
    unsigned short* wtT  = (unsigned short*)(ws + 50331648ull);     // [512][1024] 1 MB
    unsigned short* w2b  = (unsigned short*)(ws + 51380224ull);     // [512][1024] 1 MB
    unsigned short* Ucat = (unsigned short*)(ws + 52428800ull);     // [2048][1024] 4 MB
    unsigned short* W1c  = (unsigned short*)(ws + 56623104ull);     // [2048][512] 2 MB
    float*          b2   = (float*)(ws + 58720256ull);              // [2048] 8 KB
    // high-water ~56 MB

    prep_all_kernel<<<2816, 256, 0, stream>>>(x, x_bf, W_out, w2b, W_in, wtT,
                                              rot, ent, b_in, Ucat, b2);
    fold_kernel<<<dim3(DMODEL / BN, 2 * DIM / BM), 256, 0, stream>>>(Ucat, wtT, W1c);
    gemm1_kernel<<<512, 512, 0, stream>>>(x_bf, W1c, b2, p);
    gemm2_ln_kernel<<<TOKENS / 32, 256, 0, stream>>>(
        p, w2b, b_out, ln_w, ln_b, out);
}

// Round 4
// 202.542 us; speedup vs baseline: 1.1074x; 1.0824x over previous
//
#include <hip/hip_runtime.h>
#include <cstdint>

#define TOKENS 16384
#define DMODEL 512
#define DIM    1024
#define NQ     10
#define NL     2
#define BM     128
#define BN     128
#define BK     32

typedef __bf16 bf16x8 __attribute__((ext_vector_type(8)));
typedef float  f32x4  __attribute__((ext_vector_type(4)));
typedef unsigned short u16x8 __attribute__((ext_vector_type(8)));

__device__ __forceinline__ float b2f(unsigned short h) {
    union { unsigned u; float f; } v; v.u = ((unsigned)h) << 16; return v.f;
}
__device__ __forceinline__ unsigned short f2b(float f) {
    unsigned u = __builtin_bit_cast(unsigned, f);
    return (unsigned short)((u + 0x7FFFu + ((u >> 16) & 1u)) >> 16);  // RNE
}
__device__ __forceinline__ float2 cmul(float2 a, float2 b) {
    return make_float2(a.x * b.x - a.y * b.y, a.x * b.y + a.y * b.x);
}
__device__ __forceinline__ float2 cadd(float2 a, float2 b) {
    return make_float2(a.x + b.x, a.y + b.y);
}
__device__ __forceinline__ void async_copy16(const void* g, void* l) {
    __builtin_amdgcn_global_load_lds((const __attribute__((address_space(1))) void*)g,
                                     (__attribute__((address_space(3))) void*)l, 16, 0, 0);
}

// ---------------------------------------------------------------------------
// prep_all: block-id branched fused prep.
// CHANGE vs prev: U rows written in pair-grouped layout —
//   Re(c) -> row 32*(c>>4) + (c&15), Im(c) -> +16  (b2 same permutation).
// fold is a row-permutation-invariant GEMM, so W1c/b2 come out in this order
// and gemm1's epilogue pair-sum becomes per-lane (no shuffles).
// ---------------------------------------------------------------------------
__global__ __launch_bounds__(256)
void prep_all_kernel(const float* __restrict__ x,  unsigned short* __restrict__ xb,
                     const float* __restrict__ w2, unsigned short* __restrict__ w2b,
                     const float* __restrict__ W_in, unsigned short* __restrict__ wtT,
                     const float* __restrict__ rot, const float* __restrict__ ent,
                     const float* __restrict__ bin,
                     unsigned short* __restrict__ U, float* __restrict__ b2) {
    const int bid = blockIdx.x;
    const int t = threadIdx.x;

    if (bid < 256) {
        // ---------------- buildU + b2 ----------------
        __shared__ float2 Gs[NL * NQ * 4];
        const int lane = t & 63;
        const int c = bid * 4 + (t >> 6);

        if (t < NL * NQ) {
            float tx = rot[t * 3 + 0] * 0.5f;
            float ty = rot[t * 3 + 1] * 0.5f;
            float tz = rot[t * 3 + 2] * 0.5f;
            float cx = cosf(tx), sx = sinf(tx);
            float cy = cosf(ty), sy = sinf(ty);
            float cz = cosf(tz), sz = sinf(tz);
            float2 rx00 = make_float2(cx, 0.f),  rx01 = make_float2(0.f, -sx);
            float2 rx10 = make_float2(0.f, -sx), rx11 = make_float2(cx, 0.f);
            float2 ry00 = make_float2(cy, 0.f),  ry01 = make_float2(-sy, 0.f);
            float2 ry10 = make_float2(sy, 0.f),  ry11 = make_float2(cy, 0.f);
            float2 m00 = cadd(cmul(ry00, rx00), cmul(ry01, rx10));
            float2 m01 = cadd(cmul(ry00, rx01), cmul(ry01, rx11));
            float2 m10 = cadd(cmul(ry10, rx00), cmul(ry11, rx10));
            float2 m11 = cadd(cmul(ry10, rx01), cmul(ry11, rx11));
            float2 e0 = make_float2(cz, -sz), e1 = make_float2(cz, sz);
            Gs[t * 4 + 0] = cmul(e0, m00);
            Gs[t * 4 + 1] = cmul(e0, m01);
            Gs[t * 4 + 2] = cmul(e1, m10);
            Gs[t * 4 + 3] = cmul(e1, m11);
        }
        float ef[NL * (NQ - 1)];
        #pragma unroll
        for (int i = 0; i < NL * (NQ - 1); i++) ef[i] = ent[i];
        __syncthreads();

        float2 amp[16];
        #pragma unroll
        for (int r = 0; r < 16; r++)
            amp[r] = make_float2((lane * 16 + r == c) ? 1.f : 0.f, 0.f);

        #pragma unroll 1
        for (int li = 0; li < NL; li++) {
            const int l = NL - 1 - li;
            #pragma unroll
            for (int r = 0; r < 16; r++) {
                int idx = lane * 16 + r;
                float ang = 0.f;
                #pragma unroll
                for (int q = 0; q < NQ - 1; q++) {
                    int both = ((idx >> (9 - q)) & 1) & ((idx >> (8 - q)) & 1);
                    if (both) ang += ef[l * (NQ - 1) + q];
                }
                amp[r] = cmul(amp[r], make_float2(cosf(ang), sinf(ang)));
            }
            const float2* Gl = Gs + l * NQ * 4;
            #pragma unroll
            for (int qq = 0; qq < NQ; qq++) {
                const int q = 9 - qq;
                float2 u00 = Gl[q * 4 + 0], u10 = Gl[q * 4 + 1];   // transposed:
                float2 u01 = Gl[q * 4 + 2], u11 = Gl[q * 4 + 3];   // u01<->u10
                if (q >= 6) {
                    const int S = 1 << (9 - q);
                    #pragma unroll
                    for (int r = 0; r < 16; r++) {
                        if (r & S) continue;
                        float2 a = amp[r], b = amp[r + S];
                        float2 n0, n1;
                        n0.x = u00.x * a.x - u00.y * a.y + u01.x * b.x - u01.y * b.y;
                        n0.y = u00.x * a.y + u00.y * a.x + u01.x * b.y + u01.y * b.x;
                        n1.x = u10.x * a.x - u10.y * a.y + u11.x * b.x - u11.y * b.y;
                        n1.y = u10.x * a.y + u10.y * a.x + u11.x * b.y + u11.y * b.x;
                        amp[r] = n0; amp[r + S] = n1;
                    }
                } else {
                    const int mask = 32 >> q;
                    int bit = (lane >> (5 - q)) & 1;
                    float2 ua = bit ? u11 : u00;
                    float2 ub = bit ? u10 : u01;
                    #pragma unroll
                    for (int r = 0; r < 16; r++) {
                        float px = __shfl_xor(amp[r].x, mask, 64);
                        float py = __shfl_xor(amp[r].y, mask, 64);
                        float nx = ua.x * amp[r].x - ua.y * amp[r].y + ub.x * px - ub.y * py;
                        float ny = ua.x * amp[r].y + ua.y * amp[r].x + ub.x * py + ub.y * px;
                        amp[r] = make_float2(nx, ny);
                    }
                }
            }
        }

        // b2 fold at full fp32 precision (pair-grouped row layout)
        float accRe = 0.f, accIm = 0.f;
        #pragma unroll
        for (int i = 0; i < 4; i++) {
            float4 bv = *(const float4*)&bin[lane * 16 + i * 4];
            accRe += amp[i * 4 + 0].x * bv.x + amp[i * 4 + 1].x * bv.y
                   + amp[i * 4 + 2].x * bv.z + amp[i * 4 + 3].x * bv.w;
            accIm += amp[i * 4 + 0].y * bv.x + amp[i * 4 + 1].y * bv.y
                   + amp[i * 4 + 2].y * bv.z + amp[i * 4 + 3].y * bv.w;
        }
        #pragma unroll
        for (int m = 1; m < 64; m <<= 1) {
            accRe += __shfl_xor(accRe, m, 64);
            accIm += __shfl_xor(accIm, m, 64);
        }
        const int nR = ((c >> 4) << 5) + (c & 15);   // pair-grouped Re row
        if (lane == 0) { b2[nR] = accRe; b2[nR + 16] = accIm; }

        u16x8 o0, o1, p0, p1;
        #pragma unroll
        for (int r = 0; r < 8; r++) {
            o0[r] = f2b(amp[r].x);     o1[r] = f2b(amp[r + 8].x);
            p0[r] = f2b(amp[r].y);     p1[r] = f2b(amp[r + 8].y);
        }
        unsigned short* rowRe = U + (size_t)nR * DIM + lane * 16;
        unsigned short* rowIm = U + (size_t)(nR + 16) * DIM + lane * 16;
        *(u16x8*)rowRe = o0; *(u16x8*)(rowRe + 8) = o1;
        *(u16x8*)rowIm = p0; *(u16x8*)(rowIm + 8) = p1;
        return;
    }

    if (bid < 768) {
        // ---------------- W_in transpose -> wtT ----------------
        __shared__ float tile[32][33];
        const int b2i = bid - 256;
        const int tx = t & 31, ty = t >> 5;   // 32x8
        const int d0 = (b2i & 15) * 32, j0 = (b2i >> 4) * 32;
        #pragma unroll
        for (int i = 0; i < 32; i += 8)
            tile[ty + i][tx] = W_in[(size_t)(j0 + ty + i) * DMODEL + d0 + tx];
        __syncthreads();
        #pragma unroll
        for (int i = 0; i < 32; i += 8)
            wtT[(size_t)(d0 + ty + i) * DIM + j0 + tx] = f2b(tile[tx][ty + i]);
        return;
    }

    // ---------------- x / W_out fp32 -> bf16 ----------------
    const int NX4 = TOKENS * DMODEL / 4;
    const int NW4 = DMODEL * DIM / 4;
    const int total = NX4 + NW4;
    const int stride = 2048 * 256;
    for (int i = (bid - 768) * 256 + t; i < total; i += stride) {
        const float* s; unsigned short* d; int j;
        if (i < NX4) { s = x;  d = xb;  j = i; }
        else         { s = w2; d = w2b; j = i - NX4; }
        float4 v = *(const float4*)&s[(size_t)j * 4];
        ushort4 o;
        o.x = f2b(v.x); o.y = f2b(v.y); o.z = f2b(v.z); o.w = f2b(v.w);
        *(ushort4*)&d[(size_t)j * 4] = o;
    }
}

// ---------------------------------------------------------------------------
// fold: W1c[j,d] = sum_k Ucat[j,k] * wtT[d,k]  (unchanged; row-permutation of
// Ucat flows through to W1c rows, which is exactly what gemm1 expects)
// ---------------------------------------------------------------------------
__global__ __launch_bounds__(256)
void fold_kernel(const unsigned short* __restrict__ A, const unsigned short* __restrict__ B,
                 unsigned short* __restrict__ C) {
    __shared__ unsigned short lds_a[BM * BK];
    __shared__ unsigned short lds_b[BN * BK];
    const int t = threadIdx.x;
    const int wave = t >> 6, lane = t & 63;
    const int wm = wave >> 1, wn = wave & 1;
    const int bm0 = blockIdx.y * BM;
    const int bn0 = blockIdx.x * BN;
    const int K = DIM, N = DMODEL;

    f32x4 acc[4][4] = {};
    const int c0 = t, c1 = t + 256;
    const int r0 = c0 >> 2, g0 = (c0 & 3) ^ ((r0 >> 1) & 3);
    const int r1 = c1 >> 2, g1 = (c1 & 3) ^ ((r1 >> 1) & 3);

    for (int k0 = 0; k0 < K; k0 += BK) {
        async_copy16(A + (size_t)(bm0 + r0) * K + k0 + g0 * 8, (char*)lds_a + wave * 1024);
        async_copy16(A + (size_t)(bm0 + r1) * K + k0 + g1 * 8, (char*)lds_a + wave * 1024 + 4096);
        async_copy16(B + (size_t)(bn0 + r0) * K + k0 + g0 * 8, (char*)lds_b + wave * 1024);
        async_copy16(B + (size_t)(bn0 + r1) * K + k0 + g1 * 8, (char*)lds_b + wave * 1024 + 4096);
        __syncthreads();

        bf16x8 af[4], bfr[4];
        #pragma unroll
        for (int i = 0; i < 4; i++) {
            int row = wm * 64 + i * 16 + (lane & 15);
            int slot = (lane >> 4) ^ ((row >> 1) & 3);
            af[i] = *(const bf16x8*)&lds_a[row * BK + slot * 8];
            int nrow = wn * 64 + i * 16 + (lane & 15);
            int nslot = (lane >> 4) ^ ((nrow >> 1) & 3);
            bfr[i] = *(const bf16x8*)&lds_b[nrow * BK + nslot * 8];
        }
        #pragma unroll
        for (int i = 0; i < 4; i++)
            #pragma unroll
            for (int j = 0; j < 4; j++)
                acc[i][j] = __builtin_amdgcn_mfma_f32_16x16x32_bf16(af[i], bfr[j], acc[i][j], 0, 0, 0);
        __syncthreads();
    }

    #pragma unroll
    for (int i = 0; i < 4; i++)
        #pragma unroll
        for (int j = 0; j < 4; j++) {
            int col = bn0 + wn * 64 + j * 16 + (lane & 15);
            #pragma unroll
            for (int r = 0; r < 4; r++) {
                int row = bm0 + wm * 64 + i * 16 + (lane >> 4) * 4 + r;
                C[(size_t)row * N + col] = f2b(acc[i][j][r]);
            }
        }
}

// ---------------------------------------------------------------------------
// gemm1 v6: K-loop identical to v4 (best measured). New epilogue: with the
// pair-grouped W1c layout, Re/Im of pair pc live in acc[i][2jp]/acc[i][2jp+1]
// of the SAME lane -> per-lane square-sum, all-lane 2B stores (no shuffles,
// no exec masking; half the store count).
// ---------------------------------------------------------------------------
__global__ __launch_bounds__(512, 2)
void gemm1_kernel(const unsigned short* __restrict__ A, const unsigned short* __restrict__ B,
                  const float* __restrict__ bias, unsigned short* __restrict__ P) {
    const int K = DMODEL;                       // 512
    __shared__ unsigned short sm[2 * 32768];    // 128 KB
    const int t = threadIdx.x;
    const int wave = t >> 6, lane = t & 63;
    const int wm = wave >> 2, wn = wave & 3;    // 2 x 4 waves
    const int laneR = lane & 15;

    const int bid = blockIdx.x;                 // 512 blocks
    const int swz = (bid & 7) * 64 + (bid >> 3);
    const int bm0 = (swz >> 3) * 256;
    const int bn0 = (swz & 7) * 256;

    const int csrc = (t & 3) ^ ((t >> 3) & 3);
    const int rowg = t >> 2;
    const unsigned aOff0 = (unsigned)(bm0 + rowg) * DMODEL + csrc * 8;
    const unsigned aOff1 = (unsigned)(bm0 + 128 + rowg) * DMODEL + csrc * 8;
    const unsigned bOff0 = (unsigned)(bn0 + rowg) * DMODEL + csrc * 8;
    const unsigned bOff1 = (unsigned)(bn0 + 128 + rowg) * DMODEL + csrc * 8;

    const int slotc = (((lane >> 4) ^ ((lane >> 1) & 3)) & 3) * 8;

    f32x4 acc[8][4] = {};

    #define G1_STAGE(nbuf, kk, kb)                                                 \
    {                                                                              \
        unsigned short* d0 = sm + (nbuf) * 32768 + (kk) * 8192 + wave * 512;       \
        async_copy16(A + aOff0 + (kb) + (kk) * 32, d0);                            \
        async_copy16(A + aOff1 + (kb) + (kk) * 32, d0 + 4096);                     \
        async_copy16(B + bOff0 + (kb) + (kk) * 32, d0 + 16384);                    \
        async_copy16(B + bOff1 + (kb) + (kk) * 32, d0 + 20480);                    \
    }

    #define G1_COMPUTE(cbuf, kk)                                                   \
    {                                                                              \
        const unsigned short* la = sm + (cbuf) * 32768 + (kk) * 8192;              \
        const unsigned short* lb = la + 16384;                                     \
        bf16x8 af[8], bfr[4];                                                      \
        _Pragma("unroll")                                                          \
        for (int i = 0; i < 8; i++)                                                \
            af[i] = *(const bf16x8*)&la[(wm * 128 + i * 16 + laneR) * 32 + slotc]; \
        _Pragma("unroll")                                                          \
        for (int j = 0; j < 4; j++)                                                \
            bfr[j] = *(const bf16x8*)&lb[(wn * 64 + j * 16 + laneR) * 32 + slotc]; \
        __builtin_amdgcn_s_setprio(1);                                             \
        _Pragma("unroll")                                                          \
        for (int i = 0; i < 8; i++)                                                \
            _Pragma("unroll")                                                      \
            for (int j = 0; j < 4; j++)                                            \
                acc[i][j] = __builtin_amdgcn_mfma_f32_16x16x32_bf16(af[i], bfr[j], acc[i][j], 0, 0, 0); \
        __builtin_amdgcn_s_setprio(0);                                             \
    }

    G1_STAGE(0, 0, 0);
    G1_STAGE(0, 1, 0);
    asm volatile("s_waitcnt vmcnt(4)" ::: "memory");
    asm volatile("s_barrier" ::: "memory");

    const int NT = K / 64;   // 8
    #pragma unroll
    for (int kt = 0; kt < 7; kt++) {
        const int cur = kt & 1, nxt = cur ^ 1;
        const unsigned kb = (unsigned)(kt + 1) * 64;
        G1_STAGE(nxt, 0, kb);
        G1_COMPUTE(cur, 0);
        asm volatile("s_waitcnt vmcnt(4)" ::: "memory");
        asm volatile("s_barrier" ::: "memory");
        G1_STAGE(nxt, 1, kb);
        G1_COMPUTE(cur, 1);
        asm volatile("s_waitcnt vmcnt(4)" ::: "memory");
        asm volatile("s_barrier" ::: "memory");
    }
    G1_COMPUTE(1, 0);
    asm volatile("s_waitcnt vmcnt(0)" ::: "memory");
    asm volatile("s_barrier" ::: "memory");
    G1_COMPUTE(1, 1);
    (void)NT;

    #undef G1_STAGE
    #undef G1_COMPUTE

    // epilogue: per-lane |y|^2 pair-sum, all-lane 2B coalesced-segment stores
    #pragma unroll
    for (int i = 0; i < 8; i++) {
        #pragma unroll
        for (int jp = 0; jp < 2; jp++) {
            int colRe = bn0 + wn * 64 + jp * 32 + laneR;
            float bRe = bias[colRe];
            float bIm = bias[colRe + 16];
            int pc = (bn0 >> 1) + wn * 32 + jp * 16 + laneR;
            #pragma unroll
            for (int r = 0; r < 4; r++) {
                int row = bm0 + wm * 128 + i * 16 + (lane >> 4) * 4 + r;
                float vr = acc[i][2 * jp][r] + bRe;
                float vi = acc[i][2 * jp + 1][r] + bIm;
                P[(size_t)row * DIM + pc] = f2b(vr * vr + vi * vi);
            }
        }
    }
}

// ---------------------------------------------------------------------------
// gemm2_ln v2: BM=64 x BN=512(full d_model), BK=64, 512 thr (8 waves 2Mx4N),
// 256 blocks (1 round, 1/CU), 144 KB double-buffered LDS, v4-style 2-phase
// counted-vmcnt schedule. B-restage cut 4x vs BM=32 version.
// Ledger (per-wave loads/phase: A-phase 5 = A(both kk)1 + Bkk0 4; B-phase 4
// = Bkk1): end of A-phase wait vmcnt(5) retires Bkk1(n); end of B-phase wait
// vmcnt(4) retires A(n+1)+Bkk0(n+1). Tail: vmcnt(0).
// ---------------------------------------------------------------------------
__global__ __launch_bounds__(512)
void gemm2_ln_kernel(const unsigned short* __restrict__ A,   // p [TOKENS][DIM]
                     const unsigned short* __restrict__ B,   // w2b [DMODEL][DIM]
                     const float* __restrict__ bias,
                     const float* __restrict__ lw, const float* __restrict__ lb,
                     float* __restrict__ out) {
    // elems: buf*36864 + { A: kk*2048 + row*32 + slot*8 ;
    //                      B: 4096 + kk*16384 + row*32 + slot*8 }
    __shared__ unsigned short sm[2 * 36864];                 // 144 KB
    __shared__ float redS[4][64], redQ[4][64];
    __shared__ float muS[64], rsS[64], n2s[64];
    const int t = threadIdx.x, wave = t >> 6, lane = t & 63;
    const int wm = wave >> 2, wn = wave & 3;
    const int laneR = lane & 15;
    const int bm0 = blockIdx.x * 64;

    const int csrc = (t & 3) ^ ((t >> 3) & 3);
    const int akk  = t >> 8, arow = (t >> 2) & 63;
    const unsigned aSrc = (unsigned)(bm0 + arow) * DIM + akk * 32 + csrc * 8;
    const int brow = t >> 2;
    const int slotc = (((lane >> 4) ^ ((lane >> 1) & 3)) & 3) * 8;

    f32x4 acc[2][8] = {};
    f32x4 accN[2] = {};
    bf16x8 ones;
    #pragma unroll
    for (int r = 0; r < 8; r++) ones[r] = (__bf16)1.0f;

    #define G2_STAGE_A(nbuf, kb) {                                          \
        async_copy16(A + aSrc + (kb), sm + (nbuf) * 36864 + t * 8);         \
    }
    #define G2_STAGE_B(nbuf, kk, kb) {                                      \
        unsigned short* d = sm + (nbuf) * 36864 + 4096 + (kk) * 16384 + t * 8; \
        const unsigned short* s0 = B + (size_t)brow * DIM + (kb) + (kk) * 32 + csrc * 8; \
        async_copy16(s0,                 d);                                 \
        async_copy16(s0 + 128 * DIM,     d + 4096);                         \
        async_copy16(s0 + 256 * DIM,     d + 8192);                         \
        async_copy16(s0 + 384 * DIM,     d + 12288);                        \
    }
    #define G2_COMPUTE(cbuf, kk) {                                          \
        const unsigned short* la  = sm + (cbuf) * 36864 + (kk) * 2048;      \
        const unsigned short* lbp = sm + (cbuf) * 36864 + 4096 + (kk) * 16384; \
        bf16x8 af[2], bfr[8];                                               \
        _Pragma("unroll")                                                   \
        for (int i = 0; i < 2; i++)                                         \
            af[i] = *(const bf16x8*)&la[(wm * 32 + i * 16 + laneR) * 32 + slotc]; \
        _Pragma("unroll")                                                   \
        for (int j = 0; j < 8; j++)                                         \
            bfr[j] = *(const bf16x8*)&lbp[(wn * 128 + j * 16 + laneR) * 32 + slotc]; \
        __builtin_amdgcn_s_setprio(1);                                      \
        _Pragma("unroll")                                                   \
        for (int i = 0; i < 2; i++)                                         \
            _Pragma("unroll")                                               \
            for (int j = 0; j < 8; j++)                                     \
                acc[i][j] = __builtin_amdgcn_mfma_f32_16x16x32_bf16(af[i], bfr[j], acc[i][j], 0, 0, 0); \
        if (wn == 0) {                                                      \
            _Pragma("unroll")                                               \
            for (int i = 0; i < 2; i++)                                     \
                accN[i] = __builtin_amdgcn_mfma_f32_16x16x32_bf16(af[i], ones, accN[i], 0, 0, 0); \
        }                                                                   \
        __builtin_amdgcn_s_setprio(0);                                      \
    }

    // prologue: tile 0 (9 loads/wave); retire A(0)+Bkk0(0)
    G2_STAGE_A(0, 0); G2_STAGE_B(0, 0, 0); G2_STAGE_B(0, 1, 0);
    asm volatile("s_waitcnt vmcnt(4)" ::: "memory");
    asm volatile("s_barrier" ::: "memory");

    #pragma unroll
    for (int n = 0; n < 15; n++) {
        const int cb = n & 1, nb = cb ^ 1;
        const unsigned kb = (unsigned)(n + 1) * 64;
        // phase A
        G2_STAGE_A(nb, kb); G2_STAGE_B(nb, 0, kb);
        G2_COMPUTE(cb, 0);
        asm volatile("s_waitcnt vmcnt(5)" ::: "memory");
        asm volatile("s_barrier" ::: "memory");
        // phase B
        G2_STAGE_B(nb, 1, kb);
        G2_COMPUTE(cb, 1);
        asm volatile("s_waitcnt vmcnt(4)" ::: "memory");
        asm volatile("s_barrier" ::: "memory");
    }
    // tail tile 15 (buf 1)
    G2_COMPUTE(1, 0);
    asm volatile("s_waitcnt vmcnt(0)" ::: "memory");
    asm volatile("s_barrier" ::: "memory");
    G2_COMPUTE(1, 1);

    #undef G2_STAGE_A
    #undef G2_STAGE_B
    #undef G2_COMPUTE

    // ---- LN epilogue over 64 rows ----
    if (wn == 0 && laneR == 0) {
        #pragma unroll
        for (int i = 0; i < 2; i++)
            #pragma unroll
            for (int r = 0; r < 4; r++)
                n2s[wm * 32 + i * 16 + (lane >> 4) * 4 + r] = accN[i][r];
    }
    __syncthreads();

    float bvj[8];
    #pragma unroll
    for (int j = 0; j < 8; j++) bvj[j] = bias[wn * 128 + j * 16 + laneR];

    #pragma unroll
    for (int i = 0; i < 2; i++)
        #pragma unroll
        for (int r = 0; r < 4; r++) {
            int rl = wm * 32 + i * 16 + (lane >> 4) * 4 + r;
            float nn = 1.0f / fmaxf(n2s[rl], 1e-24f);
            float s = 0.f, q = 0.f;
            #pragma unroll
            for (int j = 0; j < 8; j++) {
                float val = acc[i][j][r] * nn + bvj[j];
                acc[i][j][r] = val;
                s += val; q += val * val;
            }
            s += __shfl_xor(s, 1, 64); q += __shfl_xor(q, 1, 64);
            s += __shfl_xor(s, 2, 64); q += __shfl_xor(q, 2, 64);
            s += __shfl_xor(s, 4, 64); q += __shfl_xor(q, 4, 64);
            s += __shfl_xor(s, 8, 64); q += __shfl_xor(q, 8, 64);
            if (laneR == 0) { redS[wn][rl] = s; redQ[wn][rl] = q; }
        }
    __syncthreads();
    if (t < 64) {
        float s = redS[0][t] + redS[1][t] + redS[2][t] + redS[3][t];
        float q = redQ[0][t] + redQ[1][t] + redQ[2][t] + redQ[3][t];
        float mu = s * (1.0f / DMODEL);
        float var = q * (1.0f / DMODEL) - mu * mu;
        muS[t] = mu;
        rsS[t] = rsqrtf(var + 1e-5f);
    }
    __syncthreads();
    #pragma unroll
    for (int i = 0; i < 2; i++)
        #pragma unroll
        for (int j = 0; j < 8; j++) {
            int col = wn * 128 + j * 16 + laneR;
            float w = lw[col], bb = lb[col];
            #pragma unroll
            for (int r = 0; r < 4; r++) {
                int rl = wm * 32 + i * 16 + (lane >> 4) * 4 + r;
                out[(size_t)(bm0 + rl) * DMODEL + col] =
                    (acc[i][j][r] - muS[rl]) * rsS[rl] * w + bb;
            }
        }
}

extern "C" void kernel_launch(void* const* d_in, const int* in_sizes, int n_in,
                              void* d_out, int out_size, void* d_ws, size_t ws_size,
                              hipStream_t stream) {
    (void)in_sizes; (void)n_in; (void)out_size; (void)ws_size;
    const float* x     = (const float*)d_in[0];
    const float* W_in  = (const float*)d_in[1];
    const float* b_in  = (const float*)d_in[2];
    const float* W_out = (const float*)d_in[3];
    const float* b_out = (const float*)d_in[4];
    const float* rot   = (const float*)d_in[5];
    const float* ent   = (const float*)d_in[6];
    const float* ln_w  = (const float*)d_in[7];
    const float* ln_b  = (const float*)d_in[8];
    float* out = (float*)d_out;

    char* ws = (char*)d_ws;
    unsigned short* p    = (unsigned short*)ws;                     // [16384][1024] 32 MB
    unsigned short* x_bf = (unsigned short*)(ws + 33554432ull);     // 16 MB
    unsigned short* wtT  = (unsigned short*)(ws + 50331648ull);     // [512][1024] 1 MB
    unsigned short* w2b  = (unsigned short*)(ws + 51380224ull);     // [512][1024] 1 MB
    unsigned short* Ucat = (unsigned short*)(ws + 52428800ull);     // [2048][1024] 4 MB
    unsigned short* W1c  = (unsigned short*)(ws + 56623104ull);     // [2048][512] 2 MB
    float*          b2   = (float*)(ws + 58720256ull);              // [2048] 8 KB
    // high-water ~56 MB

    prep_all_kernel<<<2816, 256, 0, stream>>>(x, x_bf, W_out, w2b, W_in, wtT,
                                              rot, ent, b_in, Ucat, b2);
    fold_kernel<<<dim3(DMODEL / BN, 2 * DIM / BM), 256, 0, stream>>>(Ucat, wtT, W1c);
    gemm1_kernel<<<512, 512, 0, stream>>>(x_bf, W1c, b2, p);
    gemm2_ln_kernel<<<TOKENS / 64, 512, 0, stream>>>(
        p, w2b, b_out, ln_w, ln_b, out);
}

// Round 5
// 195.929 us; speedup vs baseline: 1.1448x; 1.0338x over previous
//
#include <hip/hip_runtime.h>
#include <cstdint>

#define TOKENS 16384
#define DMODEL 512
#define DIM    1024
#define NQ     10
#define NL     2
#define BM     128
#define BN     128
#define BK     32

typedef __bf16 bf16x8 __attribute__((ext_vector_type(8)));
typedef float  f32x4  __attribute__((ext_vector_type(4)));
typedef unsigned short u16x8 __attribute__((ext_vector_type(8)));

__device__ __forceinline__ float b2f(unsigned short h) {
    union { unsigned u; float f; } v; v.u = ((unsigned)h) << 16; return v.f;
}
__device__ __forceinline__ unsigned short f2b(float f) {
    unsigned u = __builtin_bit_cast(unsigned, f);
    return (unsigned short)((u + 0x7FFFu + ((u >> 16) & 1u)) >> 16);  // RNE
}
__device__ __forceinline__ float2 cmul(float2 a, float2 b) {
    return make_float2(a.x * b.x - a.y * b.y, a.x * b.y + a.y * b.x);
}
__device__ __forceinline__ float2 cadd(float2 a, float2 b) {
    return make_float2(a.x + b.x, a.y + b.y);
}
__device__ __forceinline__ void async_copy16(const void* g, void* l) {
    __builtin_amdgcn_global_load_lds((const __attribute__((address_space(1))) void*)g,
                                     (__attribute__((address_space(3))) void*)l, 16, 0, 0);
}

// ---------------------------------------------------------------------------
// prep_all: block-id branched fused prep.  (unchanged; pair-grouped U layout)
// ---------------------------------------------------------------------------
__global__ __launch_bounds__(256)
void prep_all_kernel(const float* __restrict__ x,  unsigned short* __restrict__ xb,
                     const float* __restrict__ w2, unsigned short* __restrict__ w2b,
                     const float* __restrict__ W_in, unsigned short* __restrict__ wtT,
                     const float* __restrict__ rot, const float* __restrict__ ent,
                     const float* __restrict__ bin,
                     unsigned short* __restrict__ U, float* __restrict__ b2) {
    const int bid = blockIdx.x;
    const int t = threadIdx.x;

    if (bid < 256) {
        // ---------------- buildU + b2 ----------------
        __shared__ float2 Gs[NL * NQ * 4];
        const int lane = t & 63;
        const int c = bid * 4 + (t >> 6);

        if (t < NL * NQ) {
            float tx = rot[t * 3 + 0] * 0.5f;
            float ty = rot[t * 3 + 1] * 0.5f;
            float tz = rot[t * 3 + 2] * 0.5f;
            float cx = cosf(tx), sx = sinf(tx);
            float cy = cosf(ty), sy = sinf(ty);
            float cz = cosf(tz), sz = sinf(tz);
            float2 rx00 = make_float2(cx, 0.f),  rx01 = make_float2(0.f, -sx);
            float2 rx10 = make_float2(0.f, -sx), rx11 = make_float2(cx, 0.f);
            float2 ry00 = make_float2(cy, 0.f),  ry01 = make_float2(-sy, 0.f);
            float2 ry10 = make_float2(sy, 0.f),  ry11 = make_float2(cy, 0.f);
            float2 m00 = cadd(cmul(ry00, rx00), cmul(ry01, rx10));
            float2 m01 = cadd(cmul(ry00, rx01), cmul(ry01, rx11));
            float2 m10 = cadd(cmul(ry10, rx00), cmul(ry11, rx10));
            float2 m11 = cadd(cmul(ry10, rx01), cmul(ry11, rx11));
            float2 e0 = make_float2(cz, -sz), e1 = make_float2(cz, sz);
            Gs[t * 4 + 0] = cmul(e0, m00);
            Gs[t * 4 + 1] = cmul(e0, m01);
            Gs[t * 4 + 2] = cmul(e1, m10);
            Gs[t * 4 + 3] = cmul(e1, m11);
        }
        float ef[NL * (NQ - 1)];
        #pragma unroll
        for (int i = 0; i < NL * (NQ - 1); i++) ef[i] = ent[i];
        __syncthreads();

        float2 amp[16];
        #pragma unroll
        for (int r = 0; r < 16; r++)
            amp[r] = make_float2((lane * 16 + r == c) ? 1.f : 0.f, 0.f);

        #pragma unroll 1
        for (int li = 0; li < NL; li++) {
            const int l = NL - 1 - li;
            #pragma unroll
            for (int r = 0; r < 16; r++) {
                int idx = lane * 16 + r;
                float ang = 0.f;
                #pragma unroll
                for (int q = 0; q < NQ - 1; q++) {
                    int both = ((idx >> (9 - q)) & 1) & ((idx >> (8 - q)) & 1);
                    if (both) ang += ef[l * (NQ - 1) + q];
                }
                amp[r] = cmul(amp[r], make_float2(cosf(ang), sinf(ang)));
            }
            const float2* Gl = Gs + l * NQ * 4;
            #pragma unroll
            for (int qq = 0; qq < NQ; qq++) {
                const int q = 9 - qq;
                float2 u00 = Gl[q * 4 + 0], u10 = Gl[q * 4 + 1];   // transposed:
                float2 u01 = Gl[q * 4 + 2], u11 = Gl[q * 4 + 3];   // u01<->u10
                if (q >= 6) {
                    const int S = 1 << (9 - q);
                    #pragma unroll
                    for (int r = 0; r < 16; r++) {
                        if (r & S) continue;
                        float2 a = amp[r], b = amp[r + S];
                        float2 n0, n1;
                        n0.x = u00.x * a.x - u00.y * a.y + u01.x * b.x - u01.y * b.y;
                        n0.y = u00.x * a.y + u00.y * a.x + u01.x * b.y + u01.y * b.x;
                        n1.x = u10.x * a.x - u10.y * a.y + u11.x * b.x - u11.y * b.y;
                        n1.y = u10.x * a.y + u10.y * a.x + u11.x * b.y + u11.y * b.x;
                        amp[r] = n0; amp[r + S] = n1;
                    }
                } else {
                    const int mask = 32 >> q;
                    int bit = (lane >> (5 - q)) & 1;
                    float2 ua = bit ? u11 : u00;
                    float2 ub = bit ? u10 : u01;
                    #pragma unroll
                    for (int r = 0; r < 16; r++) {
                        float px = __shfl_xor(amp[r].x, mask, 64);
                        float py = __shfl_xor(amp[r].y, mask, 64);
                        float nx = ua.x * amp[r].x - ua.y * amp[r].y + ub.x * px - ub.y * py;
                        float ny = ua.x * amp[r].y + ua.y * amp[r].x + ub.x * py + ub.y * px;
                        amp[r] = make_float2(nx, ny);
                    }
                }
            }
        }

        // b2 fold at full fp32 precision (pair-grouped row layout)
        float accRe = 0.f, accIm = 0.f;
        #pragma unroll
        for (int i = 0; i < 4; i++) {
            float4 bv = *(const float4*)&bin[lane * 16 + i * 4];
            accRe += amp[i * 4 + 0].x * bv.x + amp[i * 4 + 1].x * bv.y
                   + amp[i * 4 + 2].x * bv.z + amp[i * 4 + 3].x * bv.w;
            accIm += amp[i * 4 + 0].y * bv.x + amp[i * 4 + 1].y * bv.y
                   + amp[i * 4 + 2].y * bv.z + amp[i * 4 + 3].y * bv.w;
        }
        #pragma unroll
        for (int m = 1; m < 64; m <<= 1) {
            accRe += __shfl_xor(accRe, m, 64);
            accIm += __shfl_xor(accIm, m, 64);
        }
        const int nR = ((c >> 4) << 5) + (c & 15);   // pair-grouped Re row
        if (lane == 0) { b2[nR] = accRe; b2[nR + 16] = accIm; }

        u16x8 o0, o1, p0, p1;
        #pragma unroll
        for (int r = 0; r < 8; r++) {
            o0[r] = f2b(amp[r].x);     o1[r] = f2b(amp[r + 8].x);
            p0[r] = f2b(amp[r].y);     p1[r] = f2b(amp[r + 8].y);
        }
        unsigned short* rowRe = U + (size_t)nR * DIM + lane * 16;
        unsigned short* rowIm = U + (size_t)(nR + 16) * DIM + lane * 16;
        *(u16x8*)rowRe = o0; *(u16x8*)(rowRe + 8) = o1;
        *(u16x8*)rowIm = p0; *(u16x8*)(rowIm + 8) = p1;
        return;
    }

    if (bid < 768) {
        // ---------------- W_in transpose -> wtT ----------------
        __shared__ float tile[32][33];
        const int b2i = bid - 256;
        const int tx = t & 31, ty = t >> 5;   // 32x8
        const int d0 = (b2i & 15) * 32, j0 = (b2i >> 4) * 32;
        #pragma unroll
        for (int i = 0; i < 32; i += 8)
            tile[ty + i][tx] = W_in[(size_t)(j0 + ty + i) * DMODEL + d0 + tx];
        __syncthreads();
        #pragma unroll
        for (int i = 0; i < 32; i += 8)
            wtT[(size_t)(d0 + ty + i) * DIM + j0 + tx] = f2b(tile[tx][ty + i]);
        return;
    }

    // ---------------- x / W_out fp32 -> bf16 ----------------
    const int NX4 = TOKENS * DMODEL / 4;
    const int NW4 = DMODEL * DIM / 4;
    const int total = NX4 + NW4;
    const int stride = 2048 * 256;
    for (int i = (bid - 768) * 256 + t; i < total; i += stride) {
        const float* s; unsigned short* d; int j;
        if (i < NX4) { s = x;  d = xb;  j = i; }
        else         { s = w2; d = w2b; j = i - NX4; }
        float4 v = *(const float4*)&s[(size_t)j * 4];
        ushort4 o;
        o.x = f2b(v.x); o.y = f2b(v.y); o.z = f2b(v.z); o.w = f2b(v.w);
        *(ushort4*)&d[(size_t)j * 4] = o;
    }
}

// ---------------------------------------------------------------------------
// fold v2: W1c[j,d] = sum_k Ucat[j,k] * wtT[d,k]   (2048 x 512, K=1024)
// Retiled 64x64 -> 256 blocks (full machine, was 64), BK=64, 32 KB
// double-buffered LDS (multi-block/CU hides the per-tile drain), 256 thr
// (4 waves 2Mx2N). Swizzle: 8 slots/row, store g=(c&7)^(r&7), read
// slot ((lane>>4)+kk*4)^(row&7)  [R1-verified math, 0 bank conflicts].
// ---------------------------------------------------------------------------
__global__ __launch_bounds__(256)
void fold_kernel(const unsigned short* __restrict__ A, const unsigned short* __restrict__ B,
                 unsigned short* __restrict__ C) {
    // elems: buf*8192 + mat*4096 + row*64 + slot*8    (32 KB total)
    __shared__ unsigned short sm[2 * 8192];
    const int t = threadIdx.x;
    const int wave = t >> 6, lane = t & 63;
    const int wm = wave >> 1, wn = wave & 1;
    const int laneR = lane & 15;
    const int bm0 = blockIdx.y * 64;     // 32 M-tiles
    const int bn0 = blockIdx.x * 64;     // 8  N-tiles

    // staging: chunks c0=t, c1=t+256 per mat; r=c>>3 (0..31 / 32..63),
    // src slot g=(c&7)^(r&7) — independent of which half (r+32 keeps r&7).
    const int csrc = (t & 7) ^ ((t >> 3) & 7);
    const int rowg = t >> 3;
    const unsigned aOff0 = (unsigned)(bm0 + rowg) * DIM + csrc * 8;
    const unsigned aOff1 = (unsigned)(bm0 + 32 + rowg) * DIM + csrc * 8;
    const unsigned bOff0 = (unsigned)(bn0 + rowg) * DIM + csrc * 8;
    const unsigned bOff1 = (unsigned)(bn0 + 32 + rowg) * DIM + csrc * 8;

    f32x4 acc[2][2] = {};

    #define F_STAGE(nbuf, kt) {                                            \
        unsigned short* d = sm + (nbuf) * 8192 + t * 8;                    \
        async_copy16(A + aOff0 + (kt) * 64, d);                            \
        async_copy16(A + aOff1 + (kt) * 64, d + 2048);                     \
        async_copy16(B + bOff0 + (kt) * 64, d + 4096);                     \
        async_copy16(B + bOff1 + (kt) * 64, d + 6144);                     \
    }

    F_STAGE(0, 0);
    asm volatile("s_waitcnt vmcnt(0)" ::: "memory");
    __syncthreads();

    #pragma unroll
    for (int kt = 0; kt < 16; kt++) {
        const int cur = kt & 1;
        if (kt < 15) F_STAGE(cur ^ 1, kt + 1);
        const unsigned short* la = sm + cur * 8192;
        const unsigned short* lb = la + 4096;
        #pragma unroll
        for (int kk = 0; kk < 2; kk++) {
            bf16x8 af[2], bfr[2];
            #pragma unroll
            for (int i = 0; i < 2; i++) {
                int row = wm * 32 + i * 16 + laneR;
                int slot = ((lane >> 4) + kk * 4) ^ (row & 7);
                af[i] = *(const bf16x8*)&la[row * 64 + slot * 8];
                int nrow = wn * 32 + i * 16 + laneR;
                int nslot = ((lane >> 4) + kk * 4) ^ (nrow & 7);
                bfr[i] = *(const bf16x8*)&lb[nrow * 64 + nslot * 8];
            }
            #pragma unroll
            for (int i = 0; i < 2; i++)
                #pragma unroll
                for (int j = 0; j < 2; j++)
                    acc[i][j] = __builtin_amdgcn_mfma_f32_16x16x32_bf16(af[i], bfr[j], acc[i][j], 0, 0, 0);
        }
        asm volatile("s_waitcnt vmcnt(0)" ::: "memory");
        __syncthreads();
    }
    #undef F_STAGE

    #pragma unroll
    for (int i = 0; i < 2; i++)
        #pragma unroll
        for (int j = 0; j < 2; j++) {
            int col = bn0 + wn * 32 + j * 16 + laneR;
            #pragma unroll
            for (int r = 0; r < 4; r++) {
                int row = bm0 + wm * 32 + i * 16 + (lane >> 4) * 4 + r;
                C[(size_t)row * DMODEL + col] = f2b(acc[i][j][r]);
            }
        }
}

// ---------------------------------------------------------------------------
// gemm1 v6 (unchanged): 256x256, BK=64, 2-phase counted-vmcnt dbuf; pair-
// grouped epilogue (per-lane |y|^2, all-lane 2B stores).
// ---------------------------------------------------------------------------
__global__ __launch_bounds__(512, 2)
void gemm1_kernel(const unsigned short* __restrict__ A, const unsigned short* __restrict__ B,
                  const float* __restrict__ bias, unsigned short* __restrict__ P) {
    const int K = DMODEL;                       // 512
    __shared__ unsigned short sm[2 * 32768];    // 128 KB
    const int t = threadIdx.x;
    const int wave = t >> 6, lane = t & 63;
    const int wm = wave >> 2, wn = wave & 3;    // 2 x 4 waves
    const int laneR = lane & 15;

    const int bid = blockIdx.x;                 // 512 blocks
    const int swz = (bid & 7) * 64 + (bid >> 3);
    const int bm0 = (swz >> 3) * 256;
    const int bn0 = (swz & 7) * 256;

    const int csrc = (t & 3) ^ ((t >> 3) & 3);
    const int rowg = t >> 2;
    const unsigned aOff0 = (unsigned)(bm0 + rowg) * DMODEL + csrc * 8;
    const unsigned aOff1 = (unsigned)(bm0 + 128 + rowg) * DMODEL + csrc * 8;
    const unsigned bOff0 = (unsigned)(bn0 + rowg) * DMODEL + csrc * 8;
    const unsigned bOff1 = (unsigned)(bn0 + 128 + rowg) * DMODEL + csrc * 8;

    const int slotc = (((lane >> 4) ^ ((lane >> 1) & 3)) & 3) * 8;

    f32x4 acc[8][4] = {};

    #define G1_STAGE(nbuf, kk, kb)                                                 \
    {                                                                              \
        unsigned short* d0 = sm + (nbuf) * 32768 + (kk) * 8192 + wave * 512;       \
        async_copy16(A + aOff0 + (kb) + (kk) * 32, d0);                            \
        async_copy16(A + aOff1 + (kb) + (kk) * 32, d0 + 4096);                     \
        async_copy16(B + bOff0 + (kb) + (kk) * 32, d0 + 16384);                    \
        async_copy16(B + bOff1 + (kb) + (kk) * 32, d0 + 20480);                    \
    }

    #define G1_COMPUTE(cbuf, kk)                                                   \
    {                                                                              \
        const unsigned short* la = sm + (cbuf) * 32768 + (kk) * 8192;              \
        const unsigned short* lb = la + 16384;                                     \
        bf16x8 af[8], bfr[4];                                                      \
        _Pragma("unroll")                                                          \
        for (int i = 0; i < 8; i++)                                                \
            af[i] = *(const bf16x8*)&la[(wm * 128 + i * 16 + laneR) * 32 + slotc]; \
        _Pragma("unroll")                                                          \
        for (int j = 0; j < 4; j++)                                                \
            bfr[j] = *(const bf16x8*)&lb[(wn * 64 + j * 16 + laneR) * 32 + slotc]; \
        __builtin_amdgcn_s_setprio(1);                                             \
        _Pragma("unroll")                                                          \
        for (int i = 0; i < 8; i++)                                                \
            _Pragma("unroll")                                                      \
            for (int j = 0; j < 4; j++)                                            \
                acc[i][j] = __builtin_amdgcn_mfma_f32_16x16x32_bf16(af[i], bfr[j], acc[i][j], 0, 0, 0); \
        __builtin_amdgcn_s_setprio(0);                                             \
    }

    G1_STAGE(0, 0, 0);
    G1_STAGE(0, 1, 0);
    asm volatile("s_waitcnt vmcnt(4)" ::: "memory");
    asm volatile("s_barrier" ::: "memory");

    #pragma unroll
    for (int kt = 0; kt < 7; kt++) {
        const int cur = kt & 1, nxt = cur ^ 1;
        const unsigned kb = (unsigned)(kt + 1) * 64;
        G1_STAGE(nxt, 0, kb);
        G1_COMPUTE(cur, 0);
        asm volatile("s_waitcnt vmcnt(4)" ::: "memory");
        asm volatile("s_barrier" ::: "memory");
        G1_STAGE(nxt, 1, kb);
        G1_COMPUTE(cur, 1);
        asm volatile("s_waitcnt vmcnt(4)" ::: "memory");
        asm volatile("s_barrier" ::: "memory");
    }
    G1_COMPUTE(1, 0);
    asm volatile("s_waitcnt vmcnt(0)" ::: "memory");
    asm volatile("s_barrier" ::: "memory");
    G1_COMPUTE(1, 1);

    #undef G1_STAGE
    #undef G1_COMPUTE

    // epilogue: per-lane |y|^2 pair-sum, all-lane 2B coalesced-segment stores
    #pragma unroll
    for (int i = 0; i < 8; i++) {
        #pragma unroll
        for (int jp = 0; jp < 2; jp++) {
            int colRe = bn0 + wn * 64 + jp * 32 + laneR;
            float bRe = bias[colRe];
            float bIm = bias[colRe + 16];
            int pc = (bn0 >> 1) + wn * 32 + jp * 16 + laneR;
            #pragma unroll
            for (int r = 0; r < 4; r++) {
                int row = bm0 + wm * 128 + i * 16 + (lane >> 4) * 4 + r;
                float vr = acc[i][2 * jp][r] + bRe;
                float vi = acc[i][2 * jp + 1][r] + bIm;
                P[(size_t)row * DIM + pc] = f2b(vr * vr + vi * vi);
            }
        }
    }
}

// ---------------------------------------------------------------------------
// gemm2_ln v2 (unchanged): BM=64 x BN=512, BK=64, 512 thr, 144 KB dbuf,
// 2-phase counted-vmcnt schedule, fused n2-normalize + LayerNorm.
// ---------------------------------------------------------------------------
__global__ __launch_bounds__(512)
void gemm2_ln_kernel(const unsigned short* __restrict__ A,   // p [TOKENS][DIM]
                     const unsigned short* __restrict__ B,   // w2b [DMODEL][DIM]
                     const float* __restrict__ bias,
                     const float* __restrict__ lw, const float* __restrict__ lb,
                     float* __restrict__ out) {
    __shared__ unsigned short sm[2 * 36864];                 // 144 KB
    __shared__ float redS[4][64], redQ[4][64];
    __shared__ float muS[64], rsS[64], n2s[64];
    const int t = threadIdx.x, wave = t >> 6, lane = t & 63;
    const int wm = wave >> 2, wn = wave & 3;
    const int laneR = lane & 15;
    const int bm0 = blockIdx.x * 64;

    const int csrc = (t & 3) ^ ((t >> 3) & 3);
    const int akk  = t >> 8, arow = (t >> 2) & 63;
    const unsigned aSrc = (unsigned)(bm0 + arow) * DIM + akk * 32 + csrc * 8;
    const int brow = t >> 2;
    const int slotc = (((lane >> 4) ^ ((lane >> 1) & 3)) & 3) * 8;

    f32x4 acc[2][8] = {};
    f32x4 accN[2] = {};
    bf16x8 ones;
    #pragma unroll
    for (int r = 0; r < 8; r++) ones[r] = (__bf16)1.0f;

    #define G2_STAGE_A(nbuf, kb) {                                          \
        async_copy16(A + aSrc + (kb), sm + (nbuf) * 36864 + t * 8);         \
    }
    #define G2_STAGE_B(nbuf, kk, kb) {                                      \
        unsigned short* d = sm + (nbuf) * 36864 + 4096 + (kk) * 16384 + t * 8; \
        const unsigned short* s0 = B + (size_t)brow * DIM + (kb) + (kk) * 32 + csrc * 8; \
        async_copy16(s0,                 d);                                 \
        async_copy16(s0 + 128 * DIM,     d + 4096);                         \
        async_copy16(s0 + 256 * DIM,     d + 8192);                         \
        async_copy16(s0 + 384 * DIM,     d + 12288);                        \
    }
    #define G2_COMPUTE(cbuf, kk) {                                          \
        const unsigned short* la  = sm + (cbuf) * 36864 + (kk) * 2048;      \
        const unsigned short* lbp = sm + (cbuf) * 36864 + 4096 + (kk) * 16384; \
        bf16x8 af[2], bfr[8];                                               \
        _Pragma("unroll")                                                   \
        for (int i = 0; i < 2; i++)                                         \
            af[i] = *(const bf16x8*)&la[(wm * 32 + i * 16 + laneR) * 32 + slotc]; \
        _Pragma("unroll")                                                   \
        for (int j = 0; j < 8; j++)                                         \
            bfr[j] = *(const bf16x8*)&lbp[(wn * 128 + j * 16 + laneR) * 32 + slotc]; \
        __builtin_amdgcn_s_setprio(1);                                      \
        _Pragma("unroll")                                                   \
        for (int i = 0; i < 2; i++)                                         \
            _Pragma("unroll")                                               \
            for (int j = 0; j < 8; j++)                                     \
                acc[i][j] = __builtin_amdgcn_mfma_f32_16x16x32_bf16(af[i], bfr[j], acc[i][j], 0, 0, 0); \
        if (wn == 0) {                                                      \
            _Pragma("unroll")                                               \
            for (int i = 0; i < 2; i++)                                     \
                accN[i] = __builtin_amdgcn_mfma_f32_16x16x32_bf16(af[i], ones, accN[i], 0, 0, 0); \
        }                                                                   \
        __builtin_amdgcn_s_setprio(0);                                      \
    }

    G2_STAGE_A(0, 0); G2_STAGE_B(0, 0, 0); G2_STAGE_B(0, 1, 0);
    asm volatile("s_waitcnt vmcnt(4)" ::: "memory");
    asm volatile("s_barrier" ::: "memory");

    #pragma unroll
    for (int n = 0; n < 15; n++) {
        const int cb = n & 1, nb = cb ^ 1;
        const unsigned kb = (unsigned)(n + 1) * 64;
        G2_STAGE_A(nb, kb); G2_STAGE_B(nb, 0, kb);
        G2_COMPUTE(cb, 0);
        asm volatile("s_waitcnt vmcnt(5)" ::: "memory");
        asm volatile("s_barrier" ::: "memory");
        G2_STAGE_B(nb, 1, kb);
        G2_COMPUTE(cb, 1);
        asm volatile("s_waitcnt vmcnt(4)" ::: "memory");
        asm volatile("s_barrier" ::: "memory");
    }
    G2_COMPUTE(1, 0);
    asm volatile("s_waitcnt vmcnt(0)" ::: "memory");
    asm volatile("s_barrier" ::: "memory");
    G2_COMPUTE(1, 1);

    #undef G2_STAGE_A
    #undef G2_STAGE_B
    #undef G2_COMPUTE

    // ---- LN epilogue over 64 rows ----
    if (wn == 0 && laneR == 0) {
        #pragma unroll
        for (int i = 0; i < 2; i++)
            #pragma unroll
            for (int r = 0; r < 4; r++)
                n2s[wm * 32 + i * 16 + (lane >> 4) * 4 + r] = accN[i][r];
    }
    __syncthreads();

    float bvj[8];
    #pragma unroll
    for (int j = 0; j < 8; j++) bvj[j] = bias[wn * 128 + j * 16 + laneR];

    #pragma unroll
    for (int i = 0; i < 2; i++)
        #pragma unroll
        for (int r = 0; r < 4; r++) {
            int rl = wm * 32 + i * 16 + (lane >> 4) * 4 + r;
            float nn = 1.0f / fmaxf(n2s[rl], 1e-24f);
            float s = 0.f, q = 0.f;
            #pragma unroll
            for (int j = 0; j < 8; j++) {
                float val = acc[i][j][r] * nn + bvj[j];
                acc[i][j][r] = val;
                s += val; q += val * val;
            }
            s += __shfl_xor(s, 1, 64); q += __shfl_xor(q, 1, 64);
            s += __shfl_xor(s, 2, 64); q += __shfl_xor(q, 2, 64);
            s += __shfl_xor(s, 4, 64); q += __shfl_xor(q, 4, 64);
            s += __shfl_xor(s, 8, 64); q += __shfl_xor(q, 8, 64);
            if (laneR == 0) { redS[wn][rl] = s; redQ[wn][rl] = q; }
        }
    __syncthreads();
    if (t < 64) {
        float s = redS[0][t] + redS[1][t] + redS[2][t] + redS[3][t];
        float q = redQ[0][t] + redQ[1][t] + redQ[2][t] + redQ[3][t];
        float mu = s * (1.0f / DMODEL);
        float var = q * (1.0f / DMODEL) - mu * mu;
        muS[t] = mu;
        rsS[t] = rsqrtf(var + 1e-5f);
    }
    __syncthreads();
    #pragma unroll
    for (int i = 0; i < 2; i++)
        #pragma unroll
        for (int j = 0; j < 8; j++) {
            int col = wn * 128 + j * 16 + laneR;
            float w = lw[col], bb = lb[col];
            #pragma unroll
            for (int r = 0; r < 4; r++) {
                int rl = wm * 32 + i * 16 + (lane >> 4) * 4 + r;
                out[(size_t)(bm0 + rl) * DMODEL + col] =
                    (acc[i][j][r] - muS[rl]) * rsS[rl] * w + bb;
            }
        }
}

extern "C" void kernel_launch(void* const* d_in, const int* in_sizes, int n_in,
                              void* d_out, int out_size, void* d_ws, size_t ws_size,
                              hipStream_t stream) {
    (void)in_sizes; (void)n_in; (void)out_size; (void)ws_size;
    const float* x     = (const float*)d_in[0];
    const float* W_in  = (const float*)d_in[1];
    const float* b_in  = (const float*)d_in[2];
    const float* W_out = (const float*)d_in[3];
    const float* b_out = (const float*)d_in[4];
    const float* rot   = (const float*)d_in[5];
    const float* ent   = (const float*)d_in[6];
    const float* ln_w  = (const float*)d_in[7];
    const float* ln_b  = (const float*)d_in[8];
    float* out = (float*)d_out;

    char* ws = (char*)d_ws;
    unsigned short* p    = (unsigned short*)ws;                     // [16384][1024] 32 MB
    unsigned short* x_bf = (unsigned short*)(ws + 33554432ull);     // 16 MB
    unsigned short* wtT  = (unsigned short*)(ws + 50331648ull);     // [512][1024] 1 MB
    unsigned short* w2b  = (unsigned short*)(ws + 51380224ull);     // [512][1024] 1 MB
    unsigned short* Ucat = (unsigned short*)(ws + 52428800ull);     // [2048][1024] 4 MB
    unsigned short* W1c  = (unsigned short*)(ws + 56623104ull);     // [2048][512] 2 MB
    float*          b2   = (float*)(ws + 58720256ull);              // [2048] 8 KB
    // high-water ~56 MB

    prep_all_kernel<<<2816, 256, 0, stream>>>(x, x_bf, W_out, w2b, W_in, wtT,
                                              rot, ent, b_in, Ucat, b2);
    fold_kernel<<<dim3(DMODEL / 64, 2 * DIM / 64), 256, 0, stream>>>(Ucat, wtT, W1c);
    gemm1_kernel<<<512, 512, 0, stream>>>(x_bf, W1c, b2, p);
    gemm2_ln_kernel<<<TOKENS / 64, 512, 0, stream>>>(
        p, w2b, b_out, ln_w, ln_b, out);
}